// Round 10
// baseline (849.210 us; speedup 1.0000x reference)
//
#include <hip/hip_runtime.h>
#include <hip/hip_cooperative_groups.h>
#include <cstdint>

namespace cg = cooperative_groups;

typedef unsigned short u16;
typedef __bf16 bf16x8 __attribute__((ext_vector_type(8)));
typedef float f32x4 __attribute__((ext_vector_type(4)));

#define DEV __device__ __forceinline__

DEV u16 f2bf(float f) {
  union { float f; unsigned u; } v; v.f = f;
  unsigned u = v.u;
  u += 0x7FFFu + ((u >> 16) & 1u);
  return (u16)(u >> 16);
}
DEV float bf2f(u16 u) {
  union { unsigned u; float f; } v; v.u = ((unsigned)u) << 16;
  return v.f;
}

// async global->LDS, 16B per lane; LDS dest must be wave-uniform base.
DEV void load16(const u16* g, u16* l) {
  __builtin_amdgcn_global_load_lds(
      (const __attribute__((address_space(1))) unsigned int*)(const void*)g,
      (__attribute__((address_space(3))) unsigned int*)l, 16, 0, 0);
}

// ---------------- prep: all weight transposes + embedding/PE/LN (one launch) ----------------
__global__ __launch_bounds__(256) void prep_kernel(
    const float* __restrict__ qkvw, const float* __restrict__ outw,
    const float* __restrict__ w1, const float* __restrict__ w2,
    const float* __restrict__ hw, u16* __restrict__ wq_t, u16* __restrict__ wo_t,
    u16* __restrict__ w1_t, u16* __restrict__ w2_t, u16* __restrict__ wh_t,
    const int* __restrict__ ids, const float* __restrict__ emb,
    const float* __restrict__ sc, const float* __restrict__ bi,
    float* __restrict__ x, u16* __restrict__ xn) {
  int b = blockIdx.x;
  __shared__ float t[64][65];
  if (b >= 5536) {  // ---- embedding + sinusoidal PE + layernorm ----
    int lane = threadIdx.x & 63, wave = threadIdx.x >> 6;
    int row = (b - 5536) * 4 + wave;
    int id = ids[row];
    float v[8];
#pragma unroll
    for (int i = 0; i < 8; ++i) {
      int c = lane + i * 64;
      float tk = emb[(size_t)id * 512 + c];
      int dp = c & ~1;
      float dv = expf((float)dp * (-9.210340371976184f / 512.0f));
      float ang = (float)row * dv;
      float pe = (c & 1) ? cosf(ang) : sinf(ang);
      v[i] = tk + pe;
      x[(size_t)row * 512 + c] = v[i];
    }
    float s = 0.f;
#pragma unroll
    for (int i = 0; i < 8; ++i) s += v[i];
#pragma unroll
    for (int m = 32; m; m >>= 1) s += __shfl_xor(s, m, 64);
    float mu = s * (1.0f / 512.0f);
    float var = 0.f;
#pragma unroll
    for (int i = 0; i < 8; ++i) { float d = v[i] - mu; var += d * d; }
#pragma unroll
    for (int m = 32; m; m >>= 1) var += __shfl_xor(var, m, 64);
    float rs = rsqrtf(var * (1.0f / 512.0f) + 1e-5f);
    u16* orow = xn + (size_t)row * 512;
#pragma unroll
    for (int i = 0; i < 8; ++i) {
      int c = lane + i * 64;
      orow[c] = f2bf((v[i] - mu) * rs * sc[c] + bi[c]);
    }
    return;
  }
  // ---- weight transpose f32 [K][N] -> bf16 [N][K] ----
  const float* in; u16* out; int K, N, nx, ky;
  if (b < 384)       { int z = b / 192, r = b % 192; nx = r % 24; ky = r / 24;
                       in = qkvw + (size_t)z * 786432; out = wq_t + (size_t)z * 786432; N = 1536; K = 512; }
  else if (b < 512)  { int tt = b - 384, z = tt / 64, r = tt % 64; nx = r % 8; ky = r / 8;
                       in = outw + (size_t)z * 262144; out = wo_t + (size_t)z * 262144; N = 512; K = 512; }
  else if (b < 1024) { int tt = b - 512, z = tt / 256, r = tt % 256; nx = r % 32; ky = r / 32;
                       in = w1 + (size_t)z * 1048576; out = w1_t + (size_t)z * 1048576; N = 2048; K = 512; }
  else if (b < 1536) { int tt = b - 1024, z = tt / 256, r = tt % 256; nx = r % 8; ky = r / 8;
                       in = w2 + (size_t)z * 1048576; out = w2_t + (size_t)z * 1048576; N = 512; K = 2048; }
  else               { int tt = b - 1536; nx = tt % 500; ky = tt / 500;
                       in = hw; out = wh_t; N = 32000; K = 512; }
  int n0 = nx * 64, k0 = ky * 64;
  for (int e = threadIdx.x; e < 4096; e += 256) {
    int r = e >> 6, c = e & 63;
    t[r][c] = in[(size_t)(k0 + r) * N + n0 + c];
  }
  __syncthreads();
  for (int e = threadIdx.x; e < 4096; e += 256) {
    int r = e >> 6, c = e & 63;
    out[(size_t)(n0 + r) * K + k0 + c] = f2bf(t[c][r]);
  }
}

// ================= megakernel stage device functions =================

// 128x128 pipelined bf16 GEMM stage (r8-verified body). M=2048 fixed.
// EPI: 2 = bias+gelu->bf16; 4 = phi(qkv); 5 = split-K partial f32
template <int EPI>
DEV void gemm_stage(u16* ldsp, int f, int z, const u16* A, const u16* B,
                    float* outF, u16* outB, const float* bias,
                    int N, int K, int Ksplit) {
  int tid = threadIdx.x, lane = tid & 63, w = tid >> 6;
  int m0 = (f & 15) << 7, n0 = (f >> 4) << 7;
  int wr = w >> 2, wc = w & 3;
  int fr = lane & 15, kb = lane >> 4;
  int kbeg = z * Ksplit;
  int KT = Ksplit >> 6;

  auto stage = [&](int d, int u, int k0) {
    int t = u & 1;
    int row = t * 64 + w * 8 + (lane >> 3);
    int slot = (lane & 7) ^ ((lane >> 3) & 7);
    const u16* g = (u < 2 ? A + (size_t)(m0 + row) * K : B + (size_t)(n0 + row) * K)
                   + k0 + slot * 8;
    int dst = (u < 2 ? d * 8192 : 16384 + d * 8192) + t * 4096 + w * 512;
    load16(g, &ldsp[dst]);
  };
  auto rdA = [&](int d, int i, int kk) {
    int row = wr * 64 + i * 16 + fr;
    return *(const bf16x8*)&ldsp[d * 8192 + row * 64 + ((((kk << 2) | kb) ^ (fr & 7)) << 3)];
  };
  auto rdB = [&](int d, int j, int kk) {
    int row = wc * 32 + j * 16 + fr;
    return *(const bf16x8*)&ldsp[16384 + d * 8192 + row * 64 + ((((kk << 2) | kb) ^ (fr & 7)) << 3)];
  };

  f32x4 acc[4][2];
#pragma unroll
  for (int i = 0; i < 4; ++i)
#pragma unroll
    for (int j = 0; j < 2; ++j) acc[i][j] = (f32x4){0.f, 0.f, 0.f, 0.f};

#pragma unroll 1
  for (int u = 0; u < 4; ++u) stage(0, u, kbeg);
  __syncthreads();

  for (int t = 0; t < KT; ++t) {
    int d = t & 1, e = d ^ 1;
    int k1 = kbeg + ((t + 1) << 6);
    bool pre = (t + 1) < KT;
    bf16x8 aF[4], bF[2];
    if (pre) { stage(e, 0, k1); stage(e, 1, k1); }
#pragma unroll
    for (int i = 0; i < 4; ++i) aF[i] = rdA(d, i, 0);
#pragma unroll
    for (int j = 0; j < 2; ++j) bF[j] = rdB(d, j, 0);
    __builtin_amdgcn_s_setprio(1);
#pragma unroll
    for (int i = 0; i < 4; ++i)
#pragma unroll
      for (int j = 0; j < 2; ++j)
        acc[i][j] = __builtin_amdgcn_mfma_f32_16x16x32_bf16(aF[i], bF[j], acc[i][j], 0, 0, 0);
    __builtin_amdgcn_s_setprio(0);
    __builtin_amdgcn_sched_barrier(0);
    if (pre) { stage(e, 2, k1); stage(e, 3, k1); }
#pragma unroll
    for (int i = 0; i < 4; ++i) aF[i] = rdA(d, i, 1);
#pragma unroll
    for (int j = 0; j < 2; ++j) bF[j] = rdB(d, j, 1);
    __builtin_amdgcn_s_setprio(1);
#pragma unroll
    for (int i = 0; i < 4; ++i)
#pragma unroll
      for (int j = 0; j < 2; ++j)
        acc[i][j] = __builtin_amdgcn_mfma_f32_16x16x32_bf16(aF[i], bF[j], acc[i][j], 0, 0, 0);
    __builtin_amdgcn_s_setprio(0);
    __syncthreads();
  }

  int rq = lane >> 4;
#pragma unroll
  for (int i = 0; i < 4; ++i) {
#pragma unroll
    for (int j = 0; j < 2; ++j) {
      int col = n0 + wc * 32 + j * 16 + fr;
#pragma unroll
      for (int r = 0; r < 4; ++r) {
        int row = m0 + wr * 64 + i * 16 + rq * 4 + r;
        size_t o = (size_t)row * N + col;
        float vacc = acc[i][j][r];
        if (EPI == 2) {
          float t = vacc + bias[col];
          outB[o] = f2bf(0.5f * t * (1.f + erff(t * 0.70710678118654752f)));
        } else if (EPI == 4) {
          int part = col >> 9, d = col & 511, h = d >> 6, dh = d & 63;
          float wv = (part == 2) ? vacc : (vacc > 0.f ? vacc + 1.f : expf(vacc));
          outB[(size_t)part * 1048576 + (((size_t)h * 2048 + row) * 64 + dh)] = f2bf(wv);
        } else {  // 5
          outF[(size_t)z * 1048576 + o] = vacc;
        }
      }
    }
  }
}

// intra-chunk causal linear attention + chunk sums; 512 threads, 8 waves.
DEV void attn_intra_stage(u16* smem, int bid, const u16* pq, const u16* pk,
    const u16* pv, float* numer, float* denom, float* KVc, float* Ksc) {
  int c = bid & 15, h = bid >> 4;
  int s0 = c * 128;
  u16* kl = smem;              // 128*72
  u16* vl = smem + 9216;       // 128*72
  u16* kT = smem + 18432;      // 64*136
  u16* vT = smem + 27136;      // 64*136
  u16* P  = smem + 35840;      // 128*136
  int tid = threadIdx.x, lane = tid & 63, w = tid >> 6;
  int fr = lane & 15, kb = lane >> 4, rg = lane >> 4;
  const size_t base = ((size_t)h * 2048 + s0) * 64;

  for (int e = tid; e < 1024; e += 512) {
    int r = e >> 3, c8 = (e & 7) * 8;
    *(bf16x8*)&kl[r * 72 + c8] = *(const bf16x8*)&pk[base + r * 64 + c8];
    *(bf16x8*)&vl[r * 72 + c8] = *(const bf16x8*)&pv[base + r * 64 + c8];
  }
  int fi = w;  // each of 8 waves owns one 16-row tile
  const u16* qA = pq + base + (size_t)(fi * 16 + fr) * 64 + kb * 8;
  bf16x8 aQ0 = *(const bf16x8*)qA, aQ1 = *(const bf16x8*)(qA + 32);
  __syncthreads();

  // conflict-free transpose kl->kT, vl->vT (512 threads)
  {
    int dh = tid & 63, sb = tid >> 6;
#pragma unroll
    for (int b8 = 0; b8 < 2; ++b8) {
      int sbase = sb * 16 + b8 * 8;
      u16 tk[8], tv[8];
#pragma unroll
      for (int j = 0; j < 8; ++j) {
        tk[j] = kl[(sbase + j) * 72 + dh];
        tv[j] = vl[(sbase + j) * 72 + dh];
      }
      *(int4*)&kT[dh * 136 + sbase] = *(const int4*)tk;
      *(int4*)&vT[dh * 136 + sbase] = *(const int4*)tv;
    }
  }

  // S = Q K^T, causal mask, denom, P
  {
    f32x4 dsum = {0.f, 0.f, 0.f, 0.f};
    for (int fj = 0; fj <= fi; ++fj) {
      f32x4 s4 = {0.f, 0.f, 0.f, 0.f};
      bf16x8 b0 = *(const bf16x8*)&kl[(fj * 16 + fr) * 72 + kb * 8];
      bf16x8 b1 = *(const bf16x8*)&kl[(fj * 16 + fr) * 72 + kb * 8 + 32];
      s4 = __builtin_amdgcn_mfma_f32_16x16x32_bf16(aQ0, b0, s4, 0, 0, 0);
      s4 = __builtin_amdgcn_mfma_f32_16x16x32_bf16(aQ1, b1, s4, 0, 0, 0);
      int colL = fj * 16 + fr;
#pragma unroll
      for (int rr = 0; rr < 4; ++rr) {
        int rowL = fi * 16 + rg * 4 + rr;
        float mv = (colL <= rowL) ? s4[rr] : 0.f;
        dsum[rr] += mv;
        P[rowL * 136 + colL] = f2bf(mv);
      }
    }
    if ((fi & 1) == 0) {   // zero upper-diag fragment inside PV k-range
      int colL = (fi + 1) * 16 + fr;
#pragma unroll
      for (int rr = 0; rr < 4; ++rr) P[(fi * 16 + rg * 4 + rr) * 136 + colL] = 0;
    }
#pragma unroll
    for (int rr = 0; rr < 4; ++rr) {
      float v = dsum[rr];
      v += __shfl_xor(v, 1, 16); v += __shfl_xor(v, 2, 16);
      v += __shfl_xor(v, 4, 16); v += __shfl_xor(v, 8, 16);
      if (fr == 0) denom[(size_t)h * 2048 + s0 + fi * 16 + rg * 4 + rr] = v;
    }
  }
  __syncthreads();

  // numer = P V (causally clipped)
  {
    int ktmax = (fi + 2) >> 1;
    f32x4 o0 = {0,0,0,0}, o1 = {0,0,0,0}, o2 = {0,0,0,0}, o3 = {0,0,0,0};
    for (int kt = 0; kt < ktmax; ++kt) {
      bf16x8 aP = *(const bf16x8*)&P[(fi * 16 + fr) * 136 + kt * 32 + kb * 8];
      o0 = __builtin_amdgcn_mfma_f32_16x16x32_bf16(aP, *(const bf16x8*)&vT[(0 * 16 + fr) * 136 + kt * 32 + kb * 8], o0, 0, 0, 0);
      o1 = __builtin_amdgcn_mfma_f32_16x16x32_bf16(aP, *(const bf16x8*)&vT[(1 * 16 + fr) * 136 + kt * 32 + kb * 8], o1, 0, 0, 0);
      o2 = __builtin_amdgcn_mfma_f32_16x16x32_bf16(aP, *(const bf16x8*)&vT[(2 * 16 + fr) * 136 + kt * 32 + kb * 8], o2, 0, 0, 0);
      o3 = __builtin_amdgcn_mfma_f32_16x16x32_bf16(aP, *(const bf16x8*)&vT[(3 * 16 + fr) * 136 + kt * 32 + kb * 8], o3, 0, 0, 0);
    }
#pragma unroll
    for (int rr = 0; rr < 4; ++rr) {
      size_t rb = base + (size_t)(fi * 16 + rg * 4 + rr) * 64;
      numer[rb + 0 + fr]  = o0[rr];
      numer[rb + 16 + fr] = o1[rr];
      numer[rb + 32 + fr] = o2[rr];
      numer[rb + 48 + fr] = o3[rr];
    }
  }

  // KVc by waves 0..3 (i-tile = w); Ksc by wave 4
  if (w < 4) {
    f32x4 k0 = {0,0,0,0}, k1 = {0,0,0,0}, k2 = {0,0,0,0}, k3 = {0,0,0,0};
    for (int kt = 0; kt < 4; ++kt) {
      bf16x8 aK = *(const bf16x8*)&kT[(w * 16 + fr) * 136 + kt * 32 + kb * 8];
      k0 = __builtin_amdgcn_mfma_f32_16x16x32_bf16(aK, *(const bf16x8*)&vT[(0 * 16 + fr) * 136 + kt * 32 + kb * 8], k0, 0, 0, 0);
      k1 = __builtin_amdgcn_mfma_f32_16x16x32_bf16(aK, *(const bf16x8*)&vT[(1 * 16 + fr) * 136 + kt * 32 + kb * 8], k1, 0, 0, 0);
      k2 = __builtin_amdgcn_mfma_f32_16x16x32_bf16(aK, *(const bf16x8*)&vT[(2 * 16 + fr) * 136 + kt * 32 + kb * 8], k2, 0, 0, 0);
      k3 = __builtin_amdgcn_mfma_f32_16x16x32_bf16(aK, *(const bf16x8*)&vT[(3 * 16 + fr) * 136 + kt * 32 + kb * 8], k3, 0, 0, 0);
    }
    float* kvb = KVc + ((size_t)h * 16 + c) * 4096;
#pragma unroll
    for (int rr = 0; rr < 4; ++rr) {
      int row = w * 16 + rg * 4 + rr;
      kvb[row * 64 + 0 + fr]  = k0[rr];
      kvb[row * 64 + 16 + fr] = k1[rr];
      kvb[row * 64 + 32 + fr] = k2[rr];
      kvb[row * 64 + 48 + fr] = k3[rr];
    }
  } else if (w == 4) {
    float s = 0.f;
    for (int t8 = 0; t8 < 16; ++t8) {
      bf16x8 kv = *(const bf16x8*)&kT[lane * 136 + t8 * 8];
#pragma unroll
      for (int tt = 0; tt < 8; ++tt) s += bf2f(((const u16*)&kv)[tt]);
    }
    Ksc[((size_t)h * 16 + c) * 64 + lane] = s;
  }
}

// inter-chunk prefix + finalize; 512 threads (128 rows x 4 col-quarters).
DEV void attn_inter_stage(u16* smem, int bid, const u16* pq,
    const float* numer, const float* denom, const float* KVc,
    const float* Ksc, u16* attn) {
  int c = bid & 15, h = bid >> 4;
  int s0 = c * 128;
  float* KVp = (float*)smem;      // 4096
  float* Kp  = KVp + 4096;        // 64
  float* ql  = KVp + 4160;        // 128*65
  int tid = threadIdx.x;
  for (int e = tid; e < 1024; e += 512) {
    f32x4 a = {0.f, 0.f, 0.f, 0.f};
    for (int cp = 0; cp < c; ++cp)
      a += *(const f32x4*)&KVc[((size_t)h * 16 + cp) * 4096 + e * 4];
    *(f32x4*)&KVp[e * 4] = a;
  }
  if (tid < 64) {
    float a = 0.f;
    for (int cp = 0; cp < c; ++cp) a += Ksc[((size_t)h * 16 + cp) * 64 + tid];
    Kp[tid] = a;
  }
  for (int e = tid; e < 1024; e += 512) {
    bf16x8 q8 = *(const bf16x8*)&pq[((size_t)h * 2048 + s0) * 64 + e * 8];
    int row = e >> 3, cb = (e & 7) * 8;
#pragma unroll
    for (int tt = 0; tt < 8; ++tt) ql[row * 65 + cb + tt] = bf2f(((const u16*)&q8)[tt]);
  }
  __syncthreads();
  int s = tid >> 2, q = tid & 3;
  float num[16];
  {
    const float* np_ = numer + ((size_t)h * 2048 + s0 + s) * 64 + q * 16;
#pragma unroll
    for (int i = 0; i < 4; ++i) *(f32x4*)&num[i * 4] = *(const f32x4*)&np_[i * 4];
  }
  float den = denom[(size_t)h * 2048 + s0 + s] + 1e-6f;
  for (int i = 0; i < 64; ++i) {
    float qv = ql[s * 65 + i];
    den += qv * Kp[i];
    const f32x4* kv = (const f32x4*)&KVp[i * 64 + q * 16];
#pragma unroll
    for (int j4 = 0; j4 < 4; ++j4) {
      f32x4 kvv = kv[j4];
#pragma unroll
      for (int t = 0; t < 4; ++t) num[j4 * 4 + t] += qv * kvv[t];
    }
  }
  float inv = 1.f / den;
  u16* op = attn + (size_t)(s0 + s) * 512 + h * 64 + q * 16;
#pragma unroll
  for (int j = 0; j < 16; ++j) op[j] = f2bf(num[j] * inv);
}

// split-K reduce + residual + layernorm; 256 blocks x 8 waves = 2048 rows.
DEV void reduce_ln_stage(int bid, const float* part, int nz, const float* bias,
    float* x, const float* sc, const float* bi, u16* xn) {
  int lane = threadIdx.x & 63, wave = threadIdx.x >> 6;
  int row = bid * 8 + wave;
  float* xr = x + (size_t)row * 512;
  float v[8];
#pragma unroll
  for (int i = 0; i < 8; ++i) v[i] = xr[lane + i * 64];
  if (bias) {
#pragma unroll
    for (int i = 0; i < 8; ++i) v[i] += bias[lane + i * 64];
  }
  for (int z = 0; z < nz; ++z) {
    const float* pz = part + (size_t)z * 1048576 + (size_t)row * 512;
#pragma unroll
    for (int i = 0; i < 8; ++i) v[i] += pz[lane + i * 64];
  }
#pragma unroll
  for (int i = 0; i < 8; ++i) xr[lane + i * 64] = v[i];
  float s = 0.f;
#pragma unroll
  for (int i = 0; i < 8; ++i) s += v[i];
#pragma unroll
  for (int m = 32; m; m >>= 1) s += __shfl_xor(s, m, 64);
  float mu = s * (1.0f / 512.0f);
  float var = 0.f;
#pragma unroll
  for (int i = 0; i < 8; ++i) { float d = v[i] - mu; var += d * d; }
#pragma unroll
  for (int m = 32; m; m >>= 1) var += __shfl_xor(var, m, 64);
  float rs = rsqrtf(var * (1.0f / 512.0f) + 1e-5f);
  u16* orow = xn + (size_t)row * 512;
#pragma unroll
  for (int i = 0; i < 8; ++i) {
    int c = lane + i * 64;
    orow[c] = f2bf((v[i] - mu) * rs * sc[c] + bi[c]);
  }
}

struct MegaArgs {
  const float *ln1s, *ln1b, *ln2s, *ln2b, *lnfs, *lnfb, *b1, *b2;
  const u16 *wq_t, *wo_t, *w1_t, *w2_t;
  float* x; u16* xn; u16* phiAll;
  float *numer, *denom, *KVc, *Ksc;
  u16 *attn, *hmid; float* part;
};

// ---------------- cooperative megakernel: both layers, 16 stages ----------------
__global__ __launch_bounds__(512, 1) void mega_kernel(MegaArgs a) {
  cg::grid_group grid = cg::this_grid();
  __shared__ __align__(16) u16 smem[53248];   // 106496 B union
  int bid = blockIdx.x;

  u16* phiq = a.phiAll;
  u16* phik = a.phiAll + 1048576;
  u16* vbf  = a.phiAll + 2097152;

  for (int l = 0; l < 2; ++l) {
    const u16* wq_l = a.wq_t + (size_t)l * 1536 * 512;
    const u16* wo_l = a.wo_t + (size_t)l * 512 * 512;
    const u16* w1_l = a.w1_t + (size_t)l * 2048 * 512;
    const u16* w2_l = a.w2_t + (size_t)l * 512 * 2048;

    // QKV + phi epilogue (192 tiles)
    if (bid < 192)
      gemm_stage<4>(smem, bid, 0, a.xn, wq_l, nullptr, a.phiAll, nullptr, 1536, 512, 512);
    grid.sync();
    // intra-chunk attention (128 blocks: c,h)
    if (bid < 128)
      attn_intra_stage(smem, bid, phiq, phik, vbf, a.numer, a.denom, a.KVc, a.Ksc);
    grid.sync();
    // inter-chunk prefix + finalize
    if (bid < 128)
      attn_inter_stage(smem, bid, phiq, a.numer, a.denom, a.KVc, a.Ksc, a.attn);
    grid.sync();
    // attn @ out_w, split-K=2 (128 blocks)
    if (bid < 128)
      gemm_stage<5>(smem, bid & 63, bid >> 6, a.attn, wo_l, a.part, nullptr, nullptr,
                    512, 512, 256);
    grid.sync();
    // reduce + residual + ln2
    reduce_ln_stage(bid, a.part, 2, nullptr, a.x, a.ln2s + l * 512, a.ln2b + l * 512, a.xn);
    grid.sync();
    // w1 + gelu (256 tiles)
    gemm_stage<2>(smem, bid, 0, a.xn, w1_l, nullptr, a.hmid, a.b1 + l * 2048, 2048, 512, 512);
    grid.sync();
    // w2, split-K=4 (256 blocks)
    gemm_stage<5>(smem, bid & 63, bid >> 6, a.hmid, w2_l, a.part, nullptr, nullptr,
                  512, 2048, 512);
    grid.sync();
    // reduce + bias + residual + (next ln1 | final lnf)
    const float* nls = (l == 0) ? a.ln1s + 512 : a.lnfs;
    const float* nlb = (l == 0) ? a.ln1b + 512 : a.lnfb;
    reduce_ln_stage(bid, a.part, 4, a.b2 + l * 512, a.x, nls, nlb, a.xn);
    grid.sync();
  }
}

// ---------------- 256x256 pipelined bf16 GEMM (head), 16x16 MFMA (r8 version) ----------------
__global__ __launch_bounds__(512, 2) void gemm256(const u16* __restrict__ A,
    const u16* __restrict__ B, float* __restrict__ C, int M, int N, int K) {
  __shared__ u16 lds[65536];  // [A0|A1|B0|B1] each 16384 u16
  int tid = threadIdx.x, lane = tid & 63, w = tid >> 6;
  int f = blockIdx.x;
  {
    int nwg = gridDim.x;
    int q = nwg >> 3;              // nwg % 8 == 0 required
    f = (f & 7) * q + (f >> 3);    // XCD-contiguous chunks
  }
  int m0 = (f & 7) << 8;           // m fastest for B-panel L2 reuse
  int n0 = (f >> 3) << 8;
  int wr = w >> 2, wc = w & 3;
  int fr = lane & 15, kb = lane >> 4;

  auto stage = [&](int d, int u, int k0) {
    int us = u & 3;
    int row = us * 64 + w * 8 + (lane >> 3);
    int slot = (lane & 7) ^ ((lane >> 3) & 7);
    const u16* g = (u < 4 ? A + (size_t)(m0 + row) * K : B + (size_t)(n0 + row) * K)
                   + k0 + slot * 8;
    int dst = (u < 4 ? d * 16384 : 32768 + d * 16384) + us * 4096 + w * 512;
    load16(g, &lds[dst]);
  };
  auto rdA = [&](int d, int i, int kk) {
    int row = wr * 128 + i * 16 + fr;
    return *(const bf16x8*)&lds[d * 16384 + row * 64 + ((((kk << 2) | kb) ^ (fr & 7)) << 3)];
  };
  auto rdB = [&](int d, int j, int kk) {
    int row = wc * 64 + j * 16 + fr;
    return *(const bf16x8*)&lds[32768 + d * 16384 + row * 64 + ((((kk << 2) | kb) ^ (fr & 7)) << 3)];
  };

  f32x4 acc[8][4];
#pragma unroll
  for (int i = 0; i < 8; ++i)
#pragma unroll
    for (int j = 0; j < 4; ++j) acc[i][j] = (f32x4){0.f, 0.f, 0.f, 0.f};

  int KT = K >> 6;
#pragma unroll 1
  for (int u = 0; u < 8; ++u) stage(0, u, 0);
  __syncthreads();

  for (int t = 0; t < KT; ++t) {
    int d = t & 1, e = d ^ 1;
    int k1 = (t + 1) << 6;
    bool pre = (t + 1) < KT;
    bf16x8 aF[4][2], bF[4][2];
    if (pre) { stage(e, 0, k1); stage(e, 1, k1); }
#pragma unroll
    for (int i = 0; i < 4; ++i) { aF[i][0] = rdA(d, i, 0); aF[i][1] = rdA(d, i, 1); }
#pragma unroll
    for (int j = 0; j < 2; ++j) { bF[j][0] = rdB(d, j, 0); bF[j][1] = rdB(d, j, 1); }
    __builtin_amdgcn_s_setprio(1);
#pragma unroll
    for (int i = 0; i < 4; ++i)
#pragma unroll
      for (int j = 0; j < 2; ++j)
#pragma unroll
        for (int kk = 0; kk < 2; ++kk)
          acc[i][j] = __builtin_amdgcn_mfma_f32_16x16x32_bf16(aF[i][kk], bF[j][kk], acc[i][j], 0, 0, 0);
    __builtin_amdgcn_s_setprio(0);
    __builtin_amdgcn_sched_barrier(0);
    if (pre) { stage(e, 2, k1); stage(e, 3, k1); }
#pragma unroll
    for (int j = 2; j < 4; ++j) { bF[j][0] = rdB(d, j, 0); bF[j][1] = rdB(d, j, 1); }
    __builtin_amdgcn_s_setprio(1);
#pragma unroll
    for (int i = 0; i < 4; ++i)
#pragma unroll
      for (int j = 2; j < 4; ++j)
#pragma unroll
        for (int kk = 0; kk < 2; ++kk)
          acc[i][j] = __builtin_amdgcn_mfma_f32_16x16x32_bf16(aF[i][kk], bF[j][kk], acc[i][j], 0, 0, 0);
    __builtin_amdgcn_s_setprio(0);
    __builtin_amdgcn_sched_barrier(0);
    if (pre) { stage(e, 4, k1); stage(e, 5, k1); }
#pragma unroll
    for (int i = 0; i < 4; ++i) { aF[i][0] = rdA(d, i + 4, 0); aF[i][1] = rdA(d, i + 4, 1); }
    __builtin_amdgcn_s_setprio(1);
#pragma unroll
    for (int i = 0; i < 4; ++i)
#pragma unroll
      for (int j = 0; j < 2; ++j)
#pragma unroll
        for (int kk = 0; kk < 2; ++kk)
          acc[i + 4][j] = __builtin_amdgcn_mfma_f32_16x16x32_bf16(aF[i][kk], bF[j][kk], acc[i + 4][j], 0, 0, 0);
    __builtin_amdgcn_s_setprio(0);
    __builtin_amdgcn_sched_barrier(0);
    if (pre) { stage(e, 6, k1); stage(e, 7, k1); }
    __builtin_amdgcn_s_setprio(1);
#pragma unroll
    for (int i = 0; i < 4; ++i)
#pragma unroll
      for (int j = 2; j < 4; ++j)
#pragma unroll
        for (int kk = 0; kk < 2; ++kk)
          acc[i + 4][j] = __builtin_amdgcn_mfma_f32_16x16x32_bf16(aF[i][kk], bF[j][kk], acc[i + 4][j], 0, 0, 0);
    __builtin_amdgcn_s_setprio(0);
    __syncthreads();
  }

  int rq = lane >> 4;
#pragma unroll
  for (int i = 0; i < 8; ++i) {
#pragma unroll
    for (int j = 0; j < 4; ++j) {
      int col = n0 + wc * 64 + j * 16 + fr;
#pragma unroll
      for (int r = 0; r < 4; ++r) {
        int row = m0 + wr * 128 + i * 16 + rq * 4 + r;
        C[(size_t)row * N + col] = acc[i][j][r];
      }
    }
  }
}

// ---------------- host launcher ----------------
extern "C" void kernel_launch(void* const* d_in, const int* in_sizes, int n_in,
                              void* d_out, int out_size, void* d_ws, size_t ws_size,
                              hipStream_t stream) {
  const int*   ids  = (const int*)d_in[0];
  const float* tok  = (const float*)d_in[1];
  const float* ln1s = (const float*)d_in[2];
  const float* ln1b = (const float*)d_in[3];
  const float* qkvw = (const float*)d_in[4];
  const float* outw = (const float*)d_in[5];
  const float* ln2s = (const float*)d_in[6];
  const float* ln2b = (const float*)d_in[7];
  const float* w1   = (const float*)d_in[8];
  const float* b1   = (const float*)d_in[9];
  const float* w2   = (const float*)d_in[10];
  const float* b2   = (const float*)d_in[11];
  const float* lnfs = (const float*)d_in[12];
  const float* lnfb = (const float*)d_in[13];
  const float* hw   = (const float*)d_in[14];
  float* out = (float*)d_out;

  char* ws = (char*)d_ws;
  size_t off = 0;
  auto carve = [&](size_t bytes) {
    char* p = ws + off;
    off = (off + bytes + 255) & ~(size_t)255;
    return p;
  };
  u16*   wq_t   = (u16*)carve(2ull * 1536 * 512 * 2);
  u16*   wo_t   = (u16*)carve(2ull * 512 * 512 * 2);
  u16*   w1_t   = (u16*)carve(2ull * 2048 * 512 * 2);
  u16*   w2_t   = (u16*)carve(2ull * 512 * 2048 * 2);
  u16*   wh_t   = (u16*)carve(32000ull * 512 * 2);
  float* x      = (float*)carve(2048ull * 512 * 4);
  u16*   xn     = (u16*)carve(2048ull * 512 * 2);
  u16*   phiAll = (u16*)carve(3ull * 8 * 2048 * 64 * 2);   // pq | pk | pv
  float* numer  = (float*)carve(8ull * 2048 * 64 * 4);
  float* denom  = (float*)carve(8ull * 2048 * 4);
  float* KVc    = (float*)carve(8ull * 16 * 4096 * 4);
  float* Ksc    = (float*)carve(8ull * 16 * 64 * 4);
  u16*   attn   = (u16*)carve(2048ull * 512 * 2);
  u16*   hmid   = (u16*)carve(2048ull * 2048 * 2);
  float* part   = (float*)carve(4ull * 2048 * 512 * 4);    // split-K partials
  (void)ws_size; (void)in_sizes; (void)n_in; (void)out_size;

  prep_kernel<<<6048, 256, 0, stream>>>(qkvw, outw, w1, w2, hw,
                                        wq_t, wo_t, w1_t, w2_t, wh_t,
                                        ids, tok, ln1s, ln1b, x, xn);

  MegaArgs ma;
  ma.ln1s = ln1s; ma.ln1b = ln1b; ma.ln2s = ln2s; ma.ln2b = ln2b;
  ma.lnfs = lnfs; ma.lnfb = lnfb; ma.b1 = b1; ma.b2 = b2;
  ma.wq_t = wq_t; ma.wo_t = wo_t; ma.w1_t = w1_t; ma.w2_t = w2_t;
  ma.x = x; ma.xn = xn; ma.phiAll = phiAll;
  ma.numer = numer; ma.denom = denom; ma.KVc = KVc; ma.Ksc = Ksc;
  ma.attn = attn; ma.hmid = hmid; ma.part = part;
  void* kargs[] = { &ma };
  hipLaunchCooperativeKernel(reinterpret_cast<void*>(mega_kernel),
                             dim3(256), dim3(512), kargs, 0, stream);

  gemm256<<<1000, 512, 0, stream>>>(xn, wh_t, out, 2048, 32000, 512);
}

// Round 11
// 359.135 us; speedup vs baseline: 2.3646x; 2.3646x over previous
//
#include <hip/hip_runtime.h>
#include <cstdint>

typedef unsigned short u16;
typedef __bf16 bf16x8 __attribute__((ext_vector_type(8)));
typedef float f32x4 __attribute__((ext_vector_type(4)));

#define DEV __device__ __forceinline__

DEV u16 f2bf(float f) {
  union { float f; unsigned u; } v; v.f = f;
  unsigned u = v.u;
  u += 0x7FFFu + ((u >> 16) & 1u);
  return (u16)(u >> 16);
}
DEV float bf2f(u16 u) {
  union { unsigned u; float f; } v; v.u = ((unsigned)u) << 16;
  return v.f;
}

// async global->LDS, 16B per lane; LDS dest must be wave-uniform base.
DEV void load16(const u16* g, u16* l) {
  __builtin_amdgcn_global_load_lds(
      (const __attribute__((address_space(1))) unsigned int*)(const void*)g,
      (__attribute__((address_space(3))) unsigned int*)l, 16, 0, 0);
}

// ---------------- prep: all weight transposes + embedding/PE/LN (one launch) ----------------
__global__ __launch_bounds__(256) void prep_kernel(
    const float* __restrict__ qkvw, const float* __restrict__ outw,
    const float* __restrict__ w1, const float* __restrict__ w2,
    const float* __restrict__ hw, u16* __restrict__ wq_t, u16* __restrict__ wo_t,
    u16* __restrict__ w1_t, u16* __restrict__ w2_t, u16* __restrict__ wh_t,
    const int* __restrict__ ids, const float* __restrict__ emb,
    const float* __restrict__ sc, const float* __restrict__ bi,
    float* __restrict__ x, u16* __restrict__ xn) {
  int b = blockIdx.x;
  __shared__ float t[64][65];
  if (b >= 5536) {  // ---- embedding + sinusoidal PE + layernorm ----
    int lane = threadIdx.x & 63, wave = threadIdx.x >> 6;
    int row = (b - 5536) * 4 + wave;
    int id = ids[row];
    float v[8];
#pragma unroll
    for (int i = 0; i < 8; ++i) {
      int c = lane + i * 64;
      float tk = emb[(size_t)id * 512 + c];
      int dp = c & ~1;
      float dv = expf((float)dp * (-9.210340371976184f / 512.0f));
      float ang = (float)row * dv;
      float pe = (c & 1) ? cosf(ang) : sinf(ang);
      v[i] = tk + pe;
      x[(size_t)row * 512 + c] = v[i];
    }
    float s = 0.f;
#pragma unroll
    for (int i = 0; i < 8; ++i) s += v[i];
#pragma unroll
    for (int m = 32; m; m >>= 1) s += __shfl_xor(s, m, 64);
    float mu = s * (1.0f / 512.0f);
    float var = 0.f;
#pragma unroll
    for (int i = 0; i < 8; ++i) { float d = v[i] - mu; var += d * d; }
#pragma unroll
    for (int m = 32; m; m >>= 1) var += __shfl_xor(var, m, 64);
    float rs = rsqrtf(var * (1.0f / 512.0f) + 1e-5f);
    u16* orow = xn + (size_t)row * 512;
#pragma unroll
    for (int i = 0; i < 8; ++i) {
      int c = lane + i * 64;
      orow[c] = f2bf((v[i] - mu) * rs * sc[c] + bi[c]);
    }
    return;
  }
  // ---- weight transpose f32 [K][N] -> bf16 [N][K] ----
  const float* in; u16* out; int K, N, nx, ky;
  if (b < 384)       { int z = b / 192, r = b % 192; nx = r % 24; ky = r / 24;
                       in = qkvw + (size_t)z * 786432; out = wq_t + (size_t)z * 786432; N = 1536; K = 512; }
  else if (b < 512)  { int tt = b - 384, z = tt / 64, r = tt % 64; nx = r % 8; ky = r / 8;
                       in = outw + (size_t)z * 262144; out = wo_t + (size_t)z * 262144; N = 512; K = 512; }
  else if (b < 1024) { int tt = b - 512, z = tt / 256, r = tt % 256; nx = r % 32; ky = r / 32;
                       in = w1 + (size_t)z * 1048576; out = w1_t + (size_t)z * 1048576; N = 2048; K = 512; }
  else if (b < 1536) { int tt = b - 1024, z = tt / 256, r = tt % 256; nx = r % 8; ky = r / 8;
                       in = w2 + (size_t)z * 1048576; out = w2_t + (size_t)z * 1048576; N = 512; K = 2048; }
  else               { int tt = b - 1536; nx = tt % 500; ky = tt / 500;
                       in = hw; out = wh_t; N = 32000; K = 512; }
  int n0 = nx * 64, k0 = ky * 64;
  for (int e = threadIdx.x; e < 4096; e += 256) {
    int r = e >> 6, c = e & 63;
    t[r][c] = in[(size_t)(k0 + r) * N + n0 + c];
  }
  __syncthreads();
  for (int e = threadIdx.x; e < 4096; e += 256) {
    int r = e >> 6, c = e & 63;
    out[(size_t)(n0 + r) * K + k0 + c] = f2bf(t[c][r]);
  }
}

// ---------------- pure layernorm: x -> xn (bf16) ----------------
__global__ __launch_bounds__(256) void ln_kernel(const float* __restrict__ x,
    const float* __restrict__ sc, const float* __restrict__ bi, u16* __restrict__ xn) {
  int lane = threadIdx.x & 63, wave = threadIdx.x >> 6;
  int row = blockIdx.x * 4 + wave;
  const float* xr = x + (size_t)row * 512;
  float v[8];
#pragma unroll
  for (int i = 0; i < 8; ++i) v[i] = xr[lane + i * 64];
  float s = 0.f;
#pragma unroll
  for (int i = 0; i < 8; ++i) s += v[i];
#pragma unroll
  for (int m = 32; m; m >>= 1) s += __shfl_xor(s, m, 64);
  float mu = s * (1.0f / 512.0f);
  float var = 0.f;
#pragma unroll
  for (int i = 0; i < 8; ++i) { float d = v[i] - mu; var += d * d; }
#pragma unroll
  for (int m = 32; m; m >>= 1) var += __shfl_xor(var, m, 64);
  float rs = rsqrtf(var * (1.0f / 512.0f) + 1e-5f);
  u16* orow = xn + (size_t)row * 512;
#pragma unroll
  for (int i = 0; i < 8; ++i) {
    int c = lane + i * 64;
    orow[c] = f2bf((v[i] - mu) * rs * sc[c] + bi[c]);
  }
}

// ---------------- intra-chunk causal linear attention + chunk sums (MFMA) ----------------
__global__ __launch_bounds__(256) void attn_intra(const u16* __restrict__ pq,
    const u16* __restrict__ pk, const u16* __restrict__ pv,
    float* __restrict__ numer, float* __restrict__ denom,
    float* __restrict__ KVc, float* __restrict__ Ksc) {
  int c = blockIdx.x, h = blockIdx.y;
  int s0 = c * 128;
  __shared__ u16 kl[128 * 72];
  __shared__ u16 vl[128 * 72];
  __shared__ u16 kT[64 * 136];
  __shared__ u16 vT[64 * 136];
  __shared__ u16 P[128 * 136];
  int tid = threadIdx.x, lane = tid & 63, w = tid >> 6;
  int fr = lane & 15, kb = lane >> 4, rg = lane >> 4;
  const size_t base = ((size_t)h * 2048 + s0) * 64;

  for (int e = tid; e < 1024; e += 256) {
    int r = e >> 3, c8 = (e & 7) * 8;
    *(bf16x8*)&kl[r * 72 + c8] = *(const bf16x8*)&pk[base + r * 64 + c8];
    *(bf16x8*)&vl[r * 72 + c8] = *(const bf16x8*)&pv[base + r * 64 + c8];
  }
  int fiA = w, fiB = 7 - w;
  const u16* qA = pq + base + (size_t)(fiA * 16 + fr) * 64 + kb * 8;
  const u16* qB = pq + base + (size_t)(fiB * 16 + fr) * 64 + kb * 8;
  bf16x8 aQ0a = *(const bf16x8*)qA, aQ1a = *(const bf16x8*)(qA + 32);
  bf16x8 aQ0b = *(const bf16x8*)qB, aQ1b = *(const bf16x8*)(qB + 32);
  __syncthreads();

  {
    int dh = tid & 63, sb = tid >> 6;
#pragma unroll
    for (int b8 = 0; b8 < 4; ++b8) {
      int sbase = sb * 32 + b8 * 8;
      u16 tk[8], tv[8];
#pragma unroll
      for (int j = 0; j < 8; ++j) {
        tk[j] = kl[(sbase + j) * 72 + dh];
        tv[j] = vl[(sbase + j) * 72 + dh];
      }
      *(int4*)&kT[dh * 136 + sbase] = *(const int4*)tk;
      *(int4*)&vT[dh * 136 + sbase] = *(const int4*)tv;
    }
  }

#pragma unroll
  for (int ph = 0; ph < 2; ++ph) {
    int fi = ph ? fiB : fiA;
    bf16x8 aQ0 = ph ? aQ0b : aQ0a, aQ1 = ph ? aQ1b : aQ1a;
    f32x4 dsum = {0.f, 0.f, 0.f, 0.f};
    for (int fj = 0; fj <= fi; ++fj) {
      f32x4 s4 = {0.f, 0.f, 0.f, 0.f};
      bf16x8 b0 = *(const bf16x8*)&kl[(fj * 16 + fr) * 72 + kb * 8];
      bf16x8 b1 = *(const bf16x8*)&kl[(fj * 16 + fr) * 72 + kb * 8 + 32];
      s4 = __builtin_amdgcn_mfma_f32_16x16x32_bf16(aQ0, b0, s4, 0, 0, 0);
      s4 = __builtin_amdgcn_mfma_f32_16x16x32_bf16(aQ1, b1, s4, 0, 0, 0);
      int colL = fj * 16 + fr;
#pragma unroll
      for (int rr = 0; rr < 4; ++rr) {
        int rowL = fi * 16 + rg * 4 + rr;
        float mv = (colL <= rowL) ? s4[rr] : 0.f;
        dsum[rr] += mv;
        P[rowL * 136 + colL] = f2bf(mv);
      }
    }
    if ((fi & 1) == 0) {
      int colL = (fi + 1) * 16 + fr;
#pragma unroll
      for (int rr = 0; rr < 4; ++rr) P[(fi * 16 + rg * 4 + rr) * 136 + colL] = 0;
    }
#pragma unroll
    for (int rr = 0; rr < 4; ++rr) {
      float v = dsum[rr];
      v += __shfl_xor(v, 1, 16); v += __shfl_xor(v, 2, 16);
      v += __shfl_xor(v, 4, 16); v += __shfl_xor(v, 8, 16);
      if (fr == 0) denom[(size_t)h * 2048 + s0 + fi * 16 + rg * 4 + rr] = v;
    }
  }
  __syncthreads();

#pragma unroll
  for (int ph = 0; ph < 2; ++ph) {
    int fi = ph ? fiB : fiA;
    int ktmax = (fi + 2) >> 1;
    f32x4 o0 = {0,0,0,0}, o1 = {0,0,0,0}, o2 = {0,0,0,0}, o3 = {0,0,0,0};
    for (int kt = 0; kt < ktmax; ++kt) {
      bf16x8 aP = *(const bf16x8*)&P[(fi * 16 + fr) * 136 + kt * 32 + kb * 8];
      o0 = __builtin_amdgcn_mfma_f32_16x16x32_bf16(aP, *(const bf16x8*)&vT[(0 * 16 + fr) * 136 + kt * 32 + kb * 8], o0, 0, 0, 0);
      o1 = __builtin_amdgcn_mfma_f32_16x16x32_bf16(aP, *(const bf16x8*)&vT[(1 * 16 + fr) * 136 + kt * 32 + kb * 8], o1, 0, 0, 0);
      o2 = __builtin_amdgcn_mfma_f32_16x16x32_bf16(aP, *(const bf16x8*)&vT[(2 * 16 + fr) * 136 + kt * 32 + kb * 8], o2, 0, 0, 0);
      o3 = __builtin_amdgcn_mfma_f32_16x16x32_bf16(aP, *(const bf16x8*)&vT[(3 * 16 + fr) * 136 + kt * 32 + kb * 8], o3, 0, 0, 0);
    }
#pragma unroll
    for (int rr = 0; rr < 4; ++rr) {
      size_t rb = base + (size_t)(fi * 16 + rg * 4 + rr) * 64;
      numer[rb + 0 + fr]  = o0[rr];
      numer[rb + 16 + fr] = o1[rr];
      numer[rb + 32 + fr] = o2[rr];
      numer[rb + 48 + fr] = o3[rr];
    }
  }

  {
    f32x4 k0 = {0,0,0,0}, k1 = {0,0,0,0}, k2 = {0,0,0,0}, k3 = {0,0,0,0};
    for (int kt = 0; kt < 4; ++kt) {
      bf16x8 aK = *(const bf16x8*)&kT[(w * 16 + fr) * 136 + kt * 32 + kb * 8];
      k0 = __builtin_amdgcn_mfma_f32_16x16x32_bf16(aK, *(const bf16x8*)&vT[(0 * 16 + fr) * 136 + kt * 32 + kb * 8], k0, 0, 0, 0);
      k1 = __builtin_amdgcn_mfma_f32_16x16x32_bf16(aK, *(const bf16x8*)&vT[(1 * 16 + fr) * 136 + kt * 32 + kb * 8], k1, 0, 0, 0);
      k2 = __builtin_amdgcn_mfma_f32_16x16x32_bf16(aK, *(const bf16x8*)&vT[(2 * 16 + fr) * 136 + kt * 32 + kb * 8], k2, 0, 0, 0);
      k3 = __builtin_amdgcn_mfma_f32_16x16x32_bf16(aK, *(const bf16x8*)&vT[(3 * 16 + fr) * 136 + kt * 32 + kb * 8], k3, 0, 0, 0);
    }
    float* kvb = KVc + ((size_t)h * 16 + c) * 4096;
#pragma unroll
    for (int rr = 0; rr < 4; ++rr) {
      int row = w * 16 + rg * 4 + rr;
      kvb[row * 64 + 0 + fr]  = k0[rr];
      kvb[row * 64 + 16 + fr] = k1[rr];
      kvb[row * 64 + 32 + fr] = k2[rr];
      kvb[row * 64 + 48 + fr] = k3[rr];
    }
  }
  if (tid < 64) {
    float s = 0.f;
    for (int t8 = 0; t8 < 16; ++t8) {
      bf16x8 kv = *(const bf16x8*)&kT[tid * 136 + t8 * 8];
#pragma unroll
      for (int tt = 0; tt < 8; ++tt) s += bf2f(((const u16*)&kv)[tt]);
    }
    Ksc[((size_t)h * 16 + c) * 64 + tid] = s;
  }
}

// ---------------- inter-chunk prefix + finalize (ql padded: conflict-free) ----------------
__global__ __launch_bounds__(256) void attn_inter(const u16* __restrict__ pq,
    const float* __restrict__ numer, const float* __restrict__ denom,
    const float* __restrict__ KVc, const float* __restrict__ Ksc,
    u16* __restrict__ attn) {
  int c = blockIdx.x, h = blockIdx.y;
  int s0 = c * 128;
  __shared__ float KVp[4096];
  __shared__ float Kp[64];
  __shared__ float ql[128 * 65];
  int tid = threadIdx.x;
  for (int e = tid; e < 1024; e += 256) {
    f32x4 a = {0.f, 0.f, 0.f, 0.f};
    for (int cp = 0; cp < c; ++cp)
      a += *(const f32x4*)&KVc[((size_t)h * 16 + cp) * 4096 + e * 4];
    *(f32x4*)&KVp[e * 4] = a;
  }
  if (tid < 64) {
    float a = 0.f;
    for (int cp = 0; cp < c; ++cp) a += Ksc[((size_t)h * 16 + cp) * 64 + tid];
    Kp[tid] = a;
  }
  for (int e = tid; e < 1024; e += 256) {
    bf16x8 q8 = *(const bf16x8*)&pq[((size_t)h * 2048 + s0) * 64 + e * 8];
    int row = e >> 3, cb = (e & 7) * 8;
#pragma unroll
    for (int tt = 0; tt < 8; ++tt) ql[row * 65 + cb + tt] = bf2f(((const u16*)&q8)[tt]);
  }
  __syncthreads();
  int s = tid >> 1, half = tid & 1;
  float num[32];
  {
    const float* np_ = numer + ((size_t)h * 2048 + s0 + s) * 64 + half * 32;
#pragma unroll
    for (int i = 0; i < 8; ++i) *(f32x4*)&num[i * 4] = *(const f32x4*)&np_[i * 4];
  }
  float den = denom[(size_t)h * 2048 + s0 + s] + 1e-6f;
  for (int i = 0; i < 64; ++i) {
    float qv = ql[s * 65 + i];
    den += qv * Kp[i];
    const f32x4* kv = (const f32x4*)&KVp[i * 64 + half * 32];
#pragma unroll
    for (int j4 = 0; j4 < 8; ++j4) {
      f32x4 kvv = kv[j4];
#pragma unroll
      for (int t = 0; t < 4; ++t) num[j4 * 4 + t] += qv * kvv[t];
    }
  }
  float inv = 1.f / den;
  u16* op = attn + (size_t)(s0 + s) * 512 + h * 64 + half * 32;
#pragma unroll
  for (int j = 0; j < 32; ++j) op[j] = f2bf(num[j] * inv);
}

// ---------------- 128x128 pipelined bf16 GEMM: C = A[M][K] * Bt[N][K]^T ----------------
// EPI: 2 = bias+gelu->bf16; 4 = phi(qkv)->bf16; 6 = residual accumulate x += acc (+bias)
template <int EPI>
__global__ __launch_bounds__(512, 2) void gemm_bt(const u16* __restrict__ A,
    const u16* __restrict__ B, float* __restrict__ outF, u16* __restrict__ outB,
    const float* __restrict__ bias, int M, int N, int K) {
  __shared__ u16 lds[32768];  // A:[2][8192] | B at 16384:[2][8192]
  int tid = threadIdx.x, lane = tid & 63, w = tid >> 6;
  int f = blockIdx.x + gridDim.x * blockIdx.y;
  int m0 = (f & 15) << 7, n0 = (f >> 4) << 7;
  int wr = w >> 2, wc = w & 3;
  int fr = lane & 15, kb = lane >> 4;
  int KT = K >> 6;

  auto stage = [&](int d, int u, int k0) {
    int t = u & 1;
    int row = t * 64 + w * 8 + (lane >> 3);
    int slot = (lane & 7) ^ ((lane >> 3) & 7);
    const u16* g = (u < 2 ? A + (size_t)(m0 + row) * K : B + (size_t)(n0 + row) * K)
                   + k0 + slot * 8;
    int dst = (u < 2 ? d * 8192 : 16384 + d * 8192) + t * 4096 + w * 512;
    load16(g, &lds[dst]);
  };
  auto rdA = [&](int d, int i, int kk) {
    int row = wr * 64 + i * 16 + fr;
    return *(const bf16x8*)&lds[d * 8192 + row * 64 + ((((kk << 2) | kb) ^ (fr & 7)) << 3)];
  };
  auto rdB = [&](int d, int j, int kk) {
    int row = wc * 32 + j * 16 + fr;
    return *(const bf16x8*)&lds[16384 + d * 8192 + row * 64 + ((((kk << 2) | kb) ^ (fr & 7)) << 3)];
  };

  f32x4 acc[4][2];
#pragma unroll
  for (int i = 0; i < 4; ++i)
#pragma unroll
    for (int j = 0; j < 2; ++j) acc[i][j] = (f32x4){0.f, 0.f, 0.f, 0.f};

#pragma unroll 1
  for (int u = 0; u < 4; ++u) stage(0, u, 0);
  __syncthreads();

  for (int t = 0; t < KT; ++t) {
    int d = t & 1, e = d ^ 1;
    int k1 = (t + 1) << 6;
    bool pre = (t + 1) < KT;
    bf16x8 aF[4], bF[2];
    if (pre) { stage(e, 0, k1); stage(e, 1, k1); }
#pragma unroll
    for (int i = 0; i < 4; ++i) aF[i] = rdA(d, i, 0);
#pragma unroll
    for (int j = 0; j < 2; ++j) bF[j] = rdB(d, j, 0);
    __builtin_amdgcn_s_setprio(1);
#pragma unroll
    for (int i = 0; i < 4; ++i)
#pragma unroll
      for (int j = 0; j < 2; ++j)
        acc[i][j] = __builtin_amdgcn_mfma_f32_16x16x32_bf16(aF[i], bF[j], acc[i][j], 0, 0, 0);
    __builtin_amdgcn_s_setprio(0);
    __builtin_amdgcn_sched_barrier(0);
    if (pre) { stage(e, 2, k1); stage(e, 3, k1); }
#pragma unroll
    for (int i = 0; i < 4; ++i) aF[i] = rdA(d, i, 1);
#pragma unroll
    for (int j = 0; j < 2; ++j) bF[j] = rdB(d, j, 1);
    __builtin_amdgcn_s_setprio(1);
#pragma unroll
    for (int i = 0; i < 4; ++i)
#pragma unroll
      for (int j = 0; j < 2; ++j)
        acc[i][j] = __builtin_amdgcn_mfma_f32_16x16x32_bf16(aF[i], bF[j], acc[i][j], 0, 0, 0);
    __builtin_amdgcn_s_setprio(0);
    __syncthreads();
  }

  int rq = lane >> 4;
#pragma unroll
  for (int i = 0; i < 4; ++i) {
#pragma unroll
    for (int j = 0; j < 2; ++j) {
      int col = n0 + wc * 32 + j * 16 + fr;
#pragma unroll
      for (int r = 0; r < 4; ++r) {
        int row = m0 + wr * 64 + i * 16 + rq * 4 + r;
        size_t o = (size_t)row * N + col;
        float vacc = acc[i][j][r];
        if (EPI == 2) {
          float t = vacc + bias[col];
          outB[o] = f2bf(0.5f * t * (1.f + erff(t * 0.70710678118654752f)));
        } else if (EPI == 4) {
          int part = col >> 9, d = col & 511, h = d >> 6, dh = d & 63;
          float wv = (part == 2) ? vacc : (vacc > 0.f ? vacc + 1.f : expf(vacc));
          outB[(size_t)part * 1048576 + (((size_t)h * 2048 + row) * 64 + dh)] = f2bf(wv);
        } else {  // 6: residual accumulate
          float add = vacc;
          if (bias) add += bias[col];
          outF[o] += add;
        }
      }
    }
  }
}

// ---------------- 256x256 pipelined bf16 GEMM (head) ----------------
__global__ __launch_bounds__(512, 2) void gemm256(const u16* __restrict__ A,
    const u16* __restrict__ B, float* __restrict__ C, int M, int N, int K) {
  __shared__ u16 lds[65536];  // [A0|A1|B0|B1] each 16384 u16
  int tid = threadIdx.x, lane = tid & 63, w = tid >> 6;
  int f = blockIdx.x;
  {
    int nwg = gridDim.x;
    int q = nwg >> 3;              // nwg % 8 == 0 required
    f = (f & 7) * q + (f >> 3);    // XCD-contiguous chunks
  }
  int m0 = (f & 7) << 8;           // m fastest for B-panel L2 reuse
  int n0 = (f >> 3) << 8;
  int wr = w >> 2, wc = w & 3;
  int fr = lane & 15, kb = lane >> 4;

  auto stage = [&](int d, int u, int k0) {
    int us = u & 3;
    int row = us * 64 + w * 8 + (lane >> 3);
    int slot = (lane & 7) ^ ((lane >> 3) & 7);
    const u16* g = (u < 4 ? A + (size_t)(m0 + row) * K : B + (size_t)(n0 + row) * K)
                   + k0 + slot * 8;
    int dst = (u < 4 ? d * 16384 : 32768 + d * 16384) + us * 4096 + w * 512;
    load16(g, &lds[dst]);
  };
  auto rdA = [&](int d, int i, int kk) {
    int row = wr * 128 + i * 16 + fr;
    return *(const bf16x8*)&lds[d * 16384 + row * 64 + ((((kk << 2) | kb) ^ (fr & 7)) << 3)];
  };
  auto rdB = [&](int d, int j, int kk) {
    int row = wc * 64 + j * 16 + fr;
    return *(const bf16x8*)&lds[32768 + d * 16384 + row * 64 + ((((kk << 2) | kb) ^ (fr & 7)) << 3)];
  };

  f32x4 acc[8][4];
#pragma unroll
  for (int i = 0; i < 8; ++i)
#pragma unroll
    for (int j = 0; j < 4; ++j) acc[i][j] = (f32x4){0.f, 0.f, 0.f, 0.f};

  int KT = K >> 6;
#pragma unroll 1
  for (int u = 0; u < 8; ++u) stage(0, u, 0);
  __syncthreads();

  for (int t = 0; t < KT; ++t) {
    int d = t & 1, e = d ^ 1;
    int k1 = (t + 1) << 6;
    bool pre = (t + 1) < KT;
    bf16x8 aF[4][2], bF[4][2];
    if (pre) { stage(e, 0, k1); stage(e, 1, k1); }
#pragma unroll
    for (int i = 0; i < 4; ++i) { aF[i][0] = rdA(d, i, 0); aF[i][1] = rdA(d, i, 1); }
#pragma unroll
    for (int j = 0; j < 2; ++j) { bF[j][0] = rdB(d, j, 0); bF[j][1] = rdB(d, j, 1); }
    __builtin_amdgcn_s_setprio(1);
#pragma unroll
    for (int i = 0; i < 4; ++i)
#pragma unroll
      for (int j = 0; j < 2; ++j)
#pragma unroll
        for (int kk = 0; kk < 2; ++kk)
          acc[i][j] = __builtin_amdgcn_mfma_f32_16x16x32_bf16(aF[i][kk], bF[j][kk], acc[i][j], 0, 0, 0);
    __builtin_amdgcn_s_setprio(0);
    __builtin_amdgcn_sched_barrier(0);
    if (pre) { stage(e, 2, k1); stage(e, 3, k1); }
#pragma unroll
    for (int j = 2; j < 4; ++j) { bF[j][0] = rdB(d, j, 0); bF[j][1] = rdB(d, j, 1); }
    __builtin_amdgcn_s_setprio(1);
#pragma unroll
    for (int i = 0; i < 4; ++i)
#pragma unroll
      for (int j = 2; j < 4; ++j)
#pragma unroll
        for (int kk = 0; kk < 2; ++kk)
          acc[i][j] = __builtin_amdgcn_mfma_f32_16x16x32_bf16(aF[i][kk], bF[j][kk], acc[i][j], 0, 0, 0);
    __builtin_amdgcn_s_setprio(0);
    __builtin_amdgcn_sched_barrier(0);
    if (pre) { stage(e, 4, k1); stage(e, 5, k1); }
#pragma unroll
    for (int i = 0; i < 4; ++i) { aF[i][0] = rdA(d, i + 4, 0); aF[i][1] = rdA(d, i + 4, 1); }
    __builtin_amdgcn_s_setprio(1);
#pragma unroll
    for (int i = 0; i < 4; ++i)
#pragma unroll
      for (int j = 0; j < 2; ++j)
#pragma unroll
        for (int kk = 0; kk < 2; ++kk)
          acc[i + 4][j] = __builtin_amdgcn_mfma_f32_16x16x32_bf16(aF[i][kk], bF[j][kk], acc[i + 4][j], 0, 0, 0);
    __builtin_amdgcn_s_setprio(0);
    __builtin_amdgcn_sched_barrier(0);
    if (pre) { stage(e, 6, k1); stage(e, 7, k1); }
    __builtin_amdgcn_s_setprio(1);
#pragma unroll
    for (int i = 0; i < 4; ++i)
#pragma unroll
      for (int j = 2; j < 4; ++j)
#pragma unroll
        for (int kk = 0; kk < 2; ++kk)
          acc[i + 4][j] = __builtin_amdgcn_mfma_f32_16x16x32_bf16(aF[i][kk], bF[j][kk], acc[i + 4][j], 0, 0, 0);
    __builtin_amdgcn_s_setprio(0);
    __syncthreads();
  }

  int rq = lane >> 4;
#pragma unroll
  for (int i = 0; i < 8; ++i) {
#pragma unroll
    for (int j = 0; j < 4; ++j) {
      int col = n0 + wc * 64 + j * 16 + fr;
#pragma unroll
      for (int r = 0; r < 4; ++r) {
        int row = m0 + wr * 128 + i * 16 + rq * 4 + r;
        C[(size_t)row * N + col] = acc[i][j][r];
      }
    }
  }
}

// ---------------- host launcher ----------------
extern "C" void kernel_launch(void* const* d_in, const int* in_sizes, int n_in,
                              void* d_out, int out_size, void* d_ws, size_t ws_size,
                              hipStream_t stream) {
  const int*   ids  = (const int*)d_in[0];
  const float* tok  = (const float*)d_in[1];
  const float* ln1s = (const float*)d_in[2];
  const float* ln1b = (const float*)d_in[3];
  const float* qkvw = (const float*)d_in[4];
  const float* outw = (const float*)d_in[5];
  const float* ln2s = (const float*)d_in[6];
  const float* ln2b = (const float*)d_in[7];
  const float* w1   = (const float*)d_in[8];
  const float* b1   = (const float*)d_in[9];
  const float* w2   = (const float*)d_in[10];
  const float* b2   = (const float*)d_in[11];
  const float* lnfs = (const float*)d_in[12];
  const float* lnfb = (const float*)d_in[13];
  const float* hw   = (const float*)d_in[14];
  float* out = (float*)d_out;

  char* ws = (char*)d_ws;
  size_t off = 0;
  auto carve = [&](size_t bytes) {
    char* p = ws + off;
    off = (off + bytes + 255) & ~(size_t)255;
    return p;
  };
  u16*   wq_t   = (u16*)carve(2ull * 1536 * 512 * 2);
  u16*   wo_t   = (u16*)carve(2ull * 512 * 512 * 2);
  u16*   w1_t   = (u16*)carve(2ull * 2048 * 512 * 2);
  u16*   w2_t   = (u16*)carve(2ull * 512 * 2048 * 2);
  u16*   wh_t   = (u16*)carve(32000ull * 512 * 2);
  float* x      = (float*)carve(2048ull * 512 * 4);
  u16*   xn     = (u16*)carve(2048ull * 512 * 2);
  u16*   phiAll = (u16*)carve(3ull * 8 * 2048 * 64 * 2);   // pq | pk | pv
  float* numer  = (float*)carve(8ull * 2048 * 64 * 4);
  float* denom  = (float*)carve(8ull * 2048 * 4);
  float* KVc    = (float*)carve(8ull * 16 * 4096 * 4);
  float* Ksc    = (float*)carve(8ull * 16 * 64 * 4);
  u16*   attn   = (u16*)carve(2048ull * 512 * 2);
  u16*   hmid   = (u16*)carve(2048ull * 2048 * 2);
  (void)ws_size; (void)in_sizes; (void)n_in; (void)out_size;

  u16* phiq = phiAll;
  u16* phik = phiAll + 1048576;
  u16* vbf  = phiAll + 2097152;

  prep_kernel<<<6048, 256, 0, stream>>>(qkvw, outw, w1, w2, hw,
                                        wq_t, wo_t, w1_t, w2_t, wh_t,
                                        ids, tok, ln1s, ln1b, x, xn);

  for (int l = 0; l < 2; ++l) {
    const u16* wq_l = wq_t + (size_t)l * 1536 * 512;
    const u16* wo_l = wo_t + (size_t)l * 512 * 512;
    const u16* w1_l = w1_t + (size_t)l * 2048 * 512;
    const u16* w2_l = w2_t + (size_t)l * 512 * 2048;
    const float* nls = (l == 0) ? ln1s + 512 : lnfs;
    const float* nlb = (l == 0) ? ln1b + 512 : lnfb;

    gemm_bt<4><<<dim3(12, 16), 512, 0, stream>>>(xn, wq_l, nullptr, phiAll, nullptr,
                                                 2048, 1536, 512);
    attn_intra<<<dim3(16, 8), 256, 0, stream>>>(phiq, phik, vbf, numer, denom, KVc, Ksc);
    attn_inter<<<dim3(16, 8), 256, 0, stream>>>(phiq, numer, denom, KVc, Ksc, attn);
    // attn @ out_w -> x += (no split-K partials)
    gemm_bt<6><<<dim3(4, 16), 512, 0, stream>>>(attn, wo_l, x, nullptr, nullptr,
                                                2048, 512, 512);
    ln_kernel<<<512, 256, 0, stream>>>(x, ln2s + l * 512, ln2b + l * 512, xn);
    gemm_bt<2><<<dim3(16, 16), 512, 0, stream>>>(xn, w1_l, nullptr, hmid, b1 + l * 2048,
                                                 2048, 2048, 512);
    // hmid @ w2 + bias -> x += (no split-K partials)
    gemm_bt<6><<<dim3(4, 16), 512, 0, stream>>>(hmid, w2_l, x, nullptr, b2 + l * 512,
                                                2048, 512, 2048);
    ln_kernel<<<512, 256, 0, stream>>>(x, nls, nlb, xn);
  }

  gemm256<<<1000, 512, 0, stream>>>(xn, wh_t, out, 2048, 32000, 512);
}

// Round 12
// 312.852 us; speedup vs baseline: 2.7144x; 1.1479x over previous
//
#include <hip/hip_runtime.h>
#include <cstdint>

typedef unsigned short u16;
typedef __bf16 bf16x8 __attribute__((ext_vector_type(8)));
typedef float f32x4 __attribute__((ext_vector_type(4)));

#define DEV __device__ __forceinline__

DEV u16 f2bf(float f) {
  union { float f; unsigned u; } v; v.f = f;
  unsigned u = v.u;
  u += 0x7FFFu + ((u >> 16) & 1u);
  return (u16)(u >> 16);
}
DEV float bf2f(u16 u) {
  union { unsigned u; float f; } v; v.u = ((unsigned)u) << 16;
  return v.f;
}

// async global->LDS, 16B per lane; LDS dest must be wave-uniform base.
DEV void load16(const u16* g, u16* l) {
  __builtin_amdgcn_global_load_lds(
      (const __attribute__((address_space(1))) unsigned int*)(const void*)g,
      (__attribute__((address_space(3))) unsigned int*)l, 16, 0, 0);
}

// ---------------- prep: all weight transposes + embedding/PE/LN (one launch) ----------------
__global__ __launch_bounds__(256) void prep_kernel(
    const float* __restrict__ qkvw, const float* __restrict__ outw,
    const float* __restrict__ w1, const float* __restrict__ w2,
    const float* __restrict__ hw, u16* __restrict__ wq_t, u16* __restrict__ wo_t,
    u16* __restrict__ w1_t, u16* __restrict__ w2_t, u16* __restrict__ wh_t,
    const int* __restrict__ ids, const float* __restrict__ emb,
    const float* __restrict__ sc, const float* __restrict__ bi,
    float* __restrict__ x, u16* __restrict__ xn) {
  int b = blockIdx.x;
  __shared__ float t[64][65];
  if (b >= 5536) {  // ---- embedding + sinusoidal PE + layernorm ----
    int lane = threadIdx.x & 63, wave = threadIdx.x >> 6;
    int row = (b - 5536) * 4 + wave;
    int id = ids[row];
    float v[8];
#pragma unroll
    for (int i = 0; i < 8; ++i) {
      int c = lane + i * 64;
      float tk = emb[(size_t)id * 512 + c];
      int dp = c & ~1;
      float dv = expf((float)dp * (-9.210340371976184f / 512.0f));
      float ang = (float)row * dv;
      float pe = (c & 1) ? cosf(ang) : sinf(ang);
      v[i] = tk + pe;
      x[(size_t)row * 512 + c] = v[i];
    }
    float s = 0.f;
#pragma unroll
    for (int i = 0; i < 8; ++i) s += v[i];
#pragma unroll
    for (int m = 32; m; m >>= 1) s += __shfl_xor(s, m, 64);
    float mu = s * (1.0f / 512.0f);
    float var = 0.f;
#pragma unroll
    for (int i = 0; i < 8; ++i) { float d = v[i] - mu; var += d * d; }
#pragma unroll
    for (int m = 32; m; m >>= 1) var += __shfl_xor(var, m, 64);
    float rs = rsqrtf(var * (1.0f / 512.0f) + 1e-5f);
    u16* orow = xn + (size_t)row * 512;
#pragma unroll
    for (int i = 0; i < 8; ++i) {
      int c = lane + i * 64;
      orow[c] = f2bf((v[i] - mu) * rs * sc[c] + bi[c]);
    }
    return;
  }
  // ---- weight transpose f32 [K][N] -> bf16 [N][K] ----
  const float* in; u16* out; int K, N, nx, ky;
  if (b < 384)       { int z = b / 192, r = b % 192; nx = r % 24; ky = r / 24;
                       in = qkvw + (size_t)z * 786432; out = wq_t + (size_t)z * 786432; N = 1536; K = 512; }
  else if (b < 512)  { int tt = b - 384, z = tt / 64, r = tt % 64; nx = r % 8; ky = r / 8;
                       in = outw + (size_t)z * 262144; out = wo_t + (size_t)z * 262144; N = 512; K = 512; }
  else if (b < 1024) { int tt = b - 512, z = tt / 256, r = tt % 256; nx = r % 32; ky = r / 32;
                       in = w1 + (size_t)z * 1048576; out = w1_t + (size_t)z * 1048576; N = 2048; K = 512; }
  else if (b < 1536) { int tt = b - 1024, z = tt / 256, r = tt % 256; nx = r % 8; ky = r / 8;
                       in = w2 + (size_t)z * 1048576; out = w2_t + (size_t)z * 1048576; N = 512; K = 2048; }
  else               { int tt = b - 1536; nx = tt % 500; ky = tt / 500;
                       in = hw; out = wh_t; N = 32000; K = 512; }
  int n0 = nx * 64, k0 = ky * 64;
  for (int e = threadIdx.x; e < 4096; e += 256) {
    int r = e >> 6, c = e & 63;
    t[r][c] = in[(size_t)(k0 + r) * N + n0 + c];
  }
  __syncthreads();
  for (int e = threadIdx.x; e < 4096; e += 256) {
    int r = e >> 6, c = e & 63;
    out[(size_t)(n0 + r) * K + k0 + c] = f2bf(t[c][r]);
  }
}

// ---------------- fused split-K reduce + residual + layernorm ----------------
__global__ __launch_bounds__(256) void reduce_ln(const float* __restrict__ part, int nz,
    const float* __restrict__ bias, float* __restrict__ x,
    const float* __restrict__ sc, const float* __restrict__ bi, u16* __restrict__ xn) {
  int lane = threadIdx.x & 63, wave = threadIdx.x >> 6;
  int row = blockIdx.x * 4 + wave;
  float* xr = x + (size_t)row * 512;
  float v[8];
#pragma unroll
  for (int i = 0; i < 8; ++i) v[i] = xr[lane + i * 64];
  if (bias) {
#pragma unroll
    for (int i = 0; i < 8; ++i) v[i] += bias[lane + i * 64];
  }
  for (int z = 0; z < nz; ++z) {
    const float* pz = part + (size_t)z * 1048576 + (size_t)row * 512;
#pragma unroll
    for (int i = 0; i < 8; ++i) v[i] += pz[lane + i * 64];
  }
#pragma unroll
  for (int i = 0; i < 8; ++i) xr[lane + i * 64] = v[i];
  float s = 0.f;
#pragma unroll
  for (int i = 0; i < 8; ++i) s += v[i];
#pragma unroll
  for (int m = 32; m; m >>= 1) s += __shfl_xor(s, m, 64);
  float mu = s * (1.0f / 512.0f);
  float var = 0.f;
#pragma unroll
  for (int i = 0; i < 8; ++i) { float d = v[i] - mu; var += d * d; }
#pragma unroll
  for (int m = 32; m; m >>= 1) var += __shfl_xor(var, m, 64);
  float rs = rsqrtf(var * (1.0f / 512.0f) + 1e-5f);
  u16* orow = xn + (size_t)row * 512;
#pragma unroll
  for (int i = 0; i < 8; ++i) {
    int c = lane + i * 64;
    orow[c] = f2bf((v[i] - mu) * rs * sc[c] + bi[c]);
  }
}

// ---------------- intra-chunk causal linear attention + chunk sums (MFMA) ----------------
__global__ __launch_bounds__(256) void attn_intra(const u16* __restrict__ pq,
    const u16* __restrict__ pk, const u16* __restrict__ pv,
    float* __restrict__ numer, float* __restrict__ denom,
    float* __restrict__ KVc, float* __restrict__ Ksc) {
  int c = blockIdx.x, h = blockIdx.y;
  int s0 = c * 128;
  __shared__ u16 kl[128 * 72];
  __shared__ u16 vl[128 * 72];
  __shared__ u16 kT[64 * 136];
  __shared__ u16 vT[64 * 136];
  __shared__ u16 P[128 * 136];
  int tid = threadIdx.x, lane = tid & 63, w = tid >> 6;
  int fr = lane & 15, kb = lane >> 4, rg = lane >> 4;
  const size_t base = ((size_t)h * 2048 + s0) * 64;

  for (int e = tid; e < 1024; e += 256) {
    int r = e >> 3, c8 = (e & 7) * 8;
    *(bf16x8*)&kl[r * 72 + c8] = *(const bf16x8*)&pk[base + r * 64 + c8];
    *(bf16x8*)&vl[r * 72 + c8] = *(const bf16x8*)&pv[base + r * 64 + c8];
  }
  int fiA = w, fiB = 7 - w;
  const u16* qA = pq + base + (size_t)(fiA * 16 + fr) * 64 + kb * 8;
  const u16* qB = pq + base + (size_t)(fiB * 16 + fr) * 64 + kb * 8;
  bf16x8 aQ0a = *(const bf16x8*)qA, aQ1a = *(const bf16x8*)(qA + 32);
  bf16x8 aQ0b = *(const bf16x8*)qB, aQ1b = *(const bf16x8*)(qB + 32);
  __syncthreads();

  {
    int dh = tid & 63, sb = tid >> 6;
#pragma unroll
    for (int b8 = 0; b8 < 4; ++b8) {
      int sbase = sb * 32 + b8 * 8;
      u16 tk[8], tv[8];
#pragma unroll
      for (int j = 0; j < 8; ++j) {
        tk[j] = kl[(sbase + j) * 72 + dh];
        tv[j] = vl[(sbase + j) * 72 + dh];
      }
      *(int4*)&kT[dh * 136 + sbase] = *(const int4*)tk;
      *(int4*)&vT[dh * 136 + sbase] = *(const int4*)tv;
    }
  }

#pragma unroll
  for (int ph = 0; ph < 2; ++ph) {
    int fi = ph ? fiB : fiA;
    bf16x8 aQ0 = ph ? aQ0b : aQ0a, aQ1 = ph ? aQ1b : aQ1a;
    f32x4 dsum = {0.f, 0.f, 0.f, 0.f};
    for (int fj = 0; fj <= fi; ++fj) {
      f32x4 s4 = {0.f, 0.f, 0.f, 0.f};
      bf16x8 b0 = *(const bf16x8*)&kl[(fj * 16 + fr) * 72 + kb * 8];
      bf16x8 b1 = *(const bf16x8*)&kl[(fj * 16 + fr) * 72 + kb * 8 + 32];
      s4 = __builtin_amdgcn_mfma_f32_16x16x32_bf16(aQ0, b0, s4, 0, 0, 0);
      s4 = __builtin_amdgcn_mfma_f32_16x16x32_bf16(aQ1, b1, s4, 0, 0, 0);
      int colL = fj * 16 + fr;
#pragma unroll
      for (int rr = 0; rr < 4; ++rr) {
        int rowL = fi * 16 + rg * 4 + rr;
        float mv = (colL <= rowL) ? s4[rr] : 0.f;
        dsum[rr] += mv;
        P[rowL * 136 + colL] = f2bf(mv);
      }
    }
    if ((fi & 1) == 0) {
      int colL = (fi + 1) * 16 + fr;
#pragma unroll
      for (int rr = 0; rr < 4; ++rr) P[(fi * 16 + rg * 4 + rr) * 136 + colL] = 0;
    }
#pragma unroll
    for (int rr = 0; rr < 4; ++rr) {
      float v = dsum[rr];
      v += __shfl_xor(v, 1, 16); v += __shfl_xor(v, 2, 16);
      v += __shfl_xor(v, 4, 16); v += __shfl_xor(v, 8, 16);
      if (fr == 0) denom[(size_t)h * 2048 + s0 + fi * 16 + rg * 4 + rr] = v;
    }
  }
  __syncthreads();

#pragma unroll
  for (int ph = 0; ph < 2; ++ph) {
    int fi = ph ? fiB : fiA;
    int ktmax = (fi + 2) >> 1;
    f32x4 o0 = {0,0,0,0}, o1 = {0,0,0,0}, o2 = {0,0,0,0}, o3 = {0,0,0,0};
    for (int kt = 0; kt < ktmax; ++kt) {
      bf16x8 aP = *(const bf16x8*)&P[(fi * 16 + fr) * 136 + kt * 32 + kb * 8];
      o0 = __builtin_amdgcn_mfma_f32_16x16x32_bf16(aP, *(const bf16x8*)&vT[(0 * 16 + fr) * 136 + kt * 32 + kb * 8], o0, 0, 0, 0);
      o1 = __builtin_amdgcn_mfma_f32_16x16x32_bf16(aP, *(const bf16x8*)&vT[(1 * 16 + fr) * 136 + kt * 32 + kb * 8], o1, 0, 0, 0);
      o2 = __builtin_amdgcn_mfma_f32_16x16x32_bf16(aP, *(const bf16x8*)&vT[(2 * 16 + fr) * 136 + kt * 32 + kb * 8], o2, 0, 0, 0);
      o3 = __builtin_amdgcn_mfma_f32_16x16x32_bf16(aP, *(const bf16x8*)&vT[(3 * 16 + fr) * 136 + kt * 32 + kb * 8], o3, 0, 0, 0);
    }
#pragma unroll
    for (int rr = 0; rr < 4; ++rr) {
      size_t rb = base + (size_t)(fi * 16 + rg * 4 + rr) * 64;
      numer[rb + 0 + fr]  = o0[rr];
      numer[rb + 16 + fr] = o1[rr];
      numer[rb + 32 + fr] = o2[rr];
      numer[rb + 48 + fr] = o3[rr];
    }
  }

  {
    f32x4 k0 = {0,0,0,0}, k1 = {0,0,0,0}, k2 = {0,0,0,0}, k3 = {0,0,0,0};
    for (int kt = 0; kt < 4; ++kt) {
      bf16x8 aK = *(const bf16x8*)&kT[(w * 16 + fr) * 136 + kt * 32 + kb * 8];
      k0 = __builtin_amdgcn_mfma_f32_16x16x32_bf16(aK, *(const bf16x8*)&vT[(0 * 16 + fr) * 136 + kt * 32 + kb * 8], k0, 0, 0, 0);
      k1 = __builtin_amdgcn_mfma_f32_16x16x32_bf16(aK, *(const bf16x8*)&vT[(1 * 16 + fr) * 136 + kt * 32 + kb * 8], k1, 0, 0, 0);
      k2 = __builtin_amdgcn_mfma_f32_16x16x32_bf16(aK, *(const bf16x8*)&vT[(2 * 16 + fr) * 136 + kt * 32 + kb * 8], k2, 0, 0, 0);
      k3 = __builtin_amdgcn_mfma_f32_16x16x32_bf16(aK, *(const bf16x8*)&vT[(3 * 16 + fr) * 136 + kt * 32 + kb * 8], k3, 0, 0, 0);
    }
    float* kvb = KVc + ((size_t)h * 16 + c) * 4096;
#pragma unroll
    for (int rr = 0; rr < 4; ++rr) {
      int row = w * 16 + rg * 4 + rr;
      kvb[row * 64 + 0 + fr]  = k0[rr];
      kvb[row * 64 + 16 + fr] = k1[rr];
      kvb[row * 64 + 32 + fr] = k2[rr];
      kvb[row * 64 + 48 + fr] = k3[rr];
    }
  }
  if (tid < 64) {
    float s = 0.f;
    for (int t8 = 0; t8 < 16; ++t8) {
      bf16x8 kv = *(const bf16x8*)&kT[tid * 136 + t8 * 8];
#pragma unroll
      for (int tt = 0; tt < 8; ++tt) s += bf2f(((const u16*)&kv)[tt]);
    }
    Ksc[((size_t)h * 16 + c) * 64 + tid] = s;
  }
}

// ---------------- inter-chunk prefix + finalize (ql padded: conflict-free) ----------------
__global__ __launch_bounds__(256) void attn_inter(const u16* __restrict__ pq,
    const float* __restrict__ numer, const float* __restrict__ denom,
    const float* __restrict__ KVc, const float* __restrict__ Ksc,
    u16* __restrict__ attn) {
  int c = blockIdx.x, h = blockIdx.y;
  int s0 = c * 128;
  __shared__ float KVp[4096];
  __shared__ float Kp[64];
  __shared__ float ql[128 * 65];
  int tid = threadIdx.x;
  for (int e = tid; e < 1024; e += 256) {
    f32x4 a = {0.f, 0.f, 0.f, 0.f};
    for (int cp = 0; cp < c; ++cp)
      a += *(const f32x4*)&KVc[((size_t)h * 16 + cp) * 4096 + e * 4];
    *(f32x4*)&KVp[e * 4] = a;
  }
  if (tid < 64) {
    float a = 0.f;
    for (int cp = 0; cp < c; ++cp) a += Ksc[((size_t)h * 16 + cp) * 64 + tid];
    Kp[tid] = a;
  }
  for (int e = tid; e < 1024; e += 256) {
    bf16x8 q8 = *(const bf16x8*)&pq[((size_t)h * 2048 + s0) * 64 + e * 8];
    int row = e >> 3, cb = (e & 7) * 8;
#pragma unroll
    for (int tt = 0; tt < 8; ++tt) ql[row * 65 + cb + tt] = bf2f(((const u16*)&q8)[tt]);
  }
  __syncthreads();
  int s = tid >> 1, half = tid & 1;
  float num[32];
  {
    const float* np_ = numer + ((size_t)h * 2048 + s0 + s) * 64 + half * 32;
#pragma unroll
    for (int i = 0; i < 8; ++i) *(f32x4*)&num[i * 4] = *(const f32x4*)&np_[i * 4];
  }
  float den = denom[(size_t)h * 2048 + s0 + s] + 1e-6f;
  for (int i = 0; i < 64; ++i) {
    float qv = ql[s * 65 + i];
    den += qv * Kp[i];
    const f32x4* kv = (const f32x4*)&KVp[i * 64 + half * 32];
#pragma unroll
    for (int j4 = 0; j4 < 8; ++j4) {
      f32x4 kvv = kv[j4];
#pragma unroll
      for (int t = 0; t < 4; ++t) num[j4 * 4 + t] += qv * kvv[t];
    }
  }
  float inv = 1.f / den;
  u16* op = attn + (size_t)(s0 + s) * 512 + h * 64 + half * 32;
#pragma unroll
  for (int j = 0; j < 32; ++j) op[j] = f2bf(num[j] * inv);
}

// ---------------- 128x128 pipelined bf16 GEMM: C = A[M][K] * Bt[N][K]^T ----------------
// EPI: 0 = store f32; 2 = bias+gelu->bf16; 4 = phi(qkv)->bf16; 5 = split-K partial f32
template <int EPI>
__global__ __launch_bounds__(512, 2) void gemm_bt(const u16* __restrict__ A,
    const u16* __restrict__ B, float* __restrict__ outF, u16* __restrict__ outB,
    const float* __restrict__ bias, int M, int N, int K, int Ksplit) {
  __shared__ u16 lds[32768];  // A:[2][8192] | B at 16384:[2][8192]
  int tid = threadIdx.x, lane = tid & 63, w = tid >> 6;
  int f = blockIdx.x + gridDim.x * blockIdx.y;
  int m0 = (f & 15) << 7, n0 = (f >> 4) << 7;
  int wr = w >> 2, wc = w & 3;
  int fr = lane & 15, kb = lane >> 4;
  int z = blockIdx.z;
  int kbeg = z * Ksplit;
  int KT = Ksplit >> 6;

  auto stage = [&](int d, int u, int k0) {
    int t = u & 1;
    int row = t * 64 + w * 8 + (lane >> 3);
    int slot = (lane & 7) ^ ((lane >> 3) & 7);
    const u16* g = (u < 2 ? A + (size_t)(m0 + row) * K : B + (size_t)(n0 + row) * K)
                   + k0 + slot * 8;
    int dst = (u < 2 ? d * 8192 : 16384 + d * 8192) + t * 4096 + w * 512;
    load16(g, &lds[dst]);
  };
  auto rdA = [&](int d, int i, int kk) {
    int row = wr * 64 + i * 16 + fr;
    return *(const bf16x8*)&lds[d * 8192 + row * 64 + ((((kk << 2) | kb) ^ (fr & 7)) << 3)];
  };
  auto rdB = [&](int d, int j, int kk) {
    int row = wc * 32 + j * 16 + fr;
    return *(const bf16x8*)&lds[16384 + d * 8192 + row * 64 + ((((kk << 2) | kb) ^ (fr & 7)) << 3)];
  };

  f32x4 acc[4][2];
#pragma unroll
  for (int i = 0; i < 4; ++i)
#pragma unroll
    for (int j = 0; j < 2; ++j) acc[i][j] = (f32x4){0.f, 0.f, 0.f, 0.f};

#pragma unroll 1
  for (int u = 0; u < 4; ++u) stage(0, u, kbeg);
  __syncthreads();

  for (int t = 0; t < KT; ++t) {
    int d = t & 1, e = d ^ 1;
    int k1 = kbeg + ((t + 1) << 6);
    bool pre = (t + 1) < KT;
    bf16x8 aF[4], bF[2];
    if (pre) { stage(e, 0, k1); stage(e, 1, k1); }
#pragma unroll
    for (int i = 0; i < 4; ++i) aF[i] = rdA(d, i, 0);
#pragma unroll
    for (int j = 0; j < 2; ++j) bF[j] = rdB(d, j, 0);
    __builtin_amdgcn_s_setprio(1);
#pragma unroll
    for (int i = 0; i < 4; ++i)
#pragma unroll
      for (int j = 0; j < 2; ++j)
        acc[i][j] = __builtin_amdgcn_mfma_f32_16x16x32_bf16(aF[i], bF[j], acc[i][j], 0, 0, 0);
    __builtin_amdgcn_s_setprio(0);
    __builtin_amdgcn_sched_barrier(0);
    if (pre) { stage(e, 2, k1); stage(e, 3, k1); }
#pragma unroll
    for (int i = 0; i < 4; ++i) aF[i] = rdA(d, i, 1);
#pragma unroll
    for (int j = 0; j < 2; ++j) bF[j] = rdB(d, j, 1);
    __builtin_amdgcn_s_setprio(1);
#pragma unroll
    for (int i = 0; i < 4; ++i)
#pragma unroll
      for (int j = 0; j < 2; ++j)
        acc[i][j] = __builtin_amdgcn_mfma_f32_16x16x32_bf16(aF[i], bF[j], acc[i][j], 0, 0, 0);
    __builtin_amdgcn_s_setprio(0);
    __syncthreads();
  }

  int rq = lane >> 4;
#pragma unroll
  for (int i = 0; i < 4; ++i) {
#pragma unroll
    for (int j = 0; j < 2; ++j) {
      int col = n0 + wc * 32 + j * 16 + fr;
#pragma unroll
      for (int r = 0; r < 4; ++r) {
        int row = m0 + wr * 64 + i * 16 + rq * 4 + r;
        size_t o = (size_t)row * N + col;
        float vacc = acc[i][j][r];
        if (EPI == 0) {
          outF[o] = vacc;
        } else if (EPI == 2) {
          float t = vacc + bias[col];
          outB[o] = f2bf(0.5f * t * (1.f + erff(t * 0.70710678118654752f)));
        } else if (EPI == 4) {
          int part = col >> 9, d = col & 511, h = d >> 6, dh = d & 63;
          float wv = (part == 2) ? vacc : (vacc > 0.f ? vacc + 1.f : expf(vacc));
          outB[(size_t)part * 1048576 + (((size_t)h * 2048 + row) * 64 + dh)] = f2bf(wv);
        } else {  // 5
          outF[(size_t)z * 1048576 + o] = vacc;
        }
      }
    }
  }
}

// ---------------- host launcher ----------------
extern "C" void kernel_launch(void* const* d_in, const int* in_sizes, int n_in,
                              void* d_out, int out_size, void* d_ws, size_t ws_size,
                              hipStream_t stream) {
  const int*   ids  = (const int*)d_in[0];
  const float* tok  = (const float*)d_in[1];
  const float* ln1s = (const float*)d_in[2];
  const float* ln1b = (const float*)d_in[3];
  const float* qkvw = (const float*)d_in[4];
  const float* outw = (const float*)d_in[5];
  const float* ln2s = (const float*)d_in[6];
  const float* ln2b = (const float*)d_in[7];
  const float* w1   = (const float*)d_in[8];
  const float* b1   = (const float*)d_in[9];
  const float* w2   = (const float*)d_in[10];
  const float* b2   = (const float*)d_in[11];
  const float* lnfs = (const float*)d_in[12];
  const float* lnfb = (const float*)d_in[13];
  const float* hw   = (const float*)d_in[14];
  float* out = (float*)d_out;

  char* ws = (char*)d_ws;
  size_t off = 0;
  auto carve = [&](size_t bytes) {
    char* p = ws + off;
    off = (off + bytes + 255) & ~(size_t)255;
    return p;
  };
  u16*   wq_t   = (u16*)carve(2ull * 1536 * 512 * 2);
  u16*   wo_t   = (u16*)carve(2ull * 512 * 512 * 2);
  u16*   w1_t   = (u16*)carve(2ull * 2048 * 512 * 2);
  u16*   w2_t   = (u16*)carve(2ull * 512 * 2048 * 2);
  u16*   wh_t   = (u16*)carve(32000ull * 512 * 2);
  float* x      = (float*)carve(2048ull * 512 * 4);
  u16*   xn     = (u16*)carve(2048ull * 512 * 2);
  u16*   phiAll = (u16*)carve(3ull * 8 * 2048 * 64 * 2);   // pq | pk | pv
  float* numer  = (float*)carve(8ull * 2048 * 64 * 4);
  float* denom  = (float*)carve(8ull * 2048 * 4);
  float* KVc    = (float*)carve(8ull * 16 * 4096 * 4);
  float* Ksc    = (float*)carve(8ull * 16 * 64 * 4);
  u16*   attn   = (u16*)carve(2048ull * 512 * 2);
  u16*   hmid   = (u16*)carve(2048ull * 2048 * 2);
  float* part   = (float*)carve(4ull * 2048 * 512 * 4);    // split-K partials
  (void)ws_size; (void)in_sizes; (void)n_in; (void)out_size;

  u16* phiq = phiAll;
  u16* phik = phiAll + 1048576;
  u16* vbf  = phiAll + 2097152;

  prep_kernel<<<6048, 256, 0, stream>>>(qkvw, outw, w1, w2, hw,
                                        wq_t, wo_t, w1_t, w2_t, wh_t,
                                        ids, tok, ln1s, ln1b, x, xn);

  for (int l = 0; l < 2; ++l) {
    const u16* wq_l = wq_t + (size_t)l * 1536 * 512;
    const u16* wo_l = wo_t + (size_t)l * 512 * 512;
    const u16* w1_l = w1_t + (size_t)l * 2048 * 512;
    const u16* w2_l = w2_t + (size_t)l * 512 * 2048;
    const float* nls = (l == 0) ? ln1s + 512 : lnfs;
    const float* nlb = (l == 0) ? ln1b + 512 : lnfb;

    gemm_bt<4><<<dim3(12, 16), 512, 0, stream>>>(xn, wq_l, nullptr, phiAll, nullptr,
                                                 2048, 1536, 512, 512);
    attn_intra<<<dim3(16, 8), 256, 0, stream>>>(phiq, phik, vbf, numer, denom, KVc, Ksc);
    attn_inter<<<dim3(16, 8), 256, 0, stream>>>(phiq, numer, denom, KVc, Ksc, attn);
    gemm_bt<5><<<dim3(4, 16, 2), 512, 0, stream>>>(attn, wo_l, part, nullptr, nullptr,
                                                   2048, 512, 512, 256);
    reduce_ln<<<512, 256, 0, stream>>>(part, 2, nullptr, x, ln2s + l * 512, ln2b + l * 512, xn);
    gemm_bt<2><<<dim3(16, 16), 512, 0, stream>>>(xn, w1_l, nullptr, hmid, b1 + l * 2048,
                                                 2048, 2048, 512, 512);
    gemm_bt<5><<<dim3(4, 16, 4), 512, 0, stream>>>(hmid, w2_l, part, nullptr, nullptr,
                                                   2048, 512, 2048, 512);
    reduce_ln<<<512, 256, 0, stream>>>(part, 4, b2 + l * 512, x, nls, nlb, xn);
  }

  // head on the 2-blocks/CU 128^2 structure; grid 4000, m-fastest for B-panel L2 reuse
  gemm_bt<0><<<dim3(4000), 512, 0, stream>>>(xn, wh_t, out, nullptr, nullptr,
                                             2048, 32000, 512, 512);
}

// Round 13
// 301.002 us; speedup vs baseline: 2.8213x; 1.0394x over previous
//
#include <hip/hip_runtime.h>
#include <cstdint>

typedef unsigned short u16;
typedef __bf16 bf16x8 __attribute__((ext_vector_type(8)));
typedef float f32x4 __attribute__((ext_vector_type(4)));

#define DEV __device__ __forceinline__

DEV u16 f2bf(float f) {
  union { float f; unsigned u; } v; v.f = f;
  unsigned u = v.u;
  u += 0x7FFFu + ((u >> 16) & 1u);
  return (u16)(u >> 16);
}
DEV float bf2f(u16 u) {
  union { unsigned u; float f; } v; v.u = ((unsigned)u) << 16;
  return v.f;
}

// async global->LDS, 16B per lane; LDS dest must be wave-uniform base.
DEV void load16(const u16* g, u16* l) {
  __builtin_amdgcn_global_load_lds(
      (const __attribute__((address_space(1))) unsigned int*)(const void*)g,
      (__attribute__((address_space(3))) unsigned int*)l, 16, 0, 0);
}

// ---------------- prep: all weight transposes + embedding/PE/LN (one launch) ----------------
__global__ __launch_bounds__(256) void prep_kernel(
    const float* __restrict__ qkvw, const float* __restrict__ outw,
    const float* __restrict__ w1, const float* __restrict__ w2,
    const float* __restrict__ hw, u16* __restrict__ wq_t, u16* __restrict__ wo_t,
    u16* __restrict__ w1_t, u16* __restrict__ w2_t, u16* __restrict__ wh_t,
    const int* __restrict__ ids, const float* __restrict__ emb,
    const float* __restrict__ sc, const float* __restrict__ bi,
    float* __restrict__ x, u16* __restrict__ xn) {
  int b = blockIdx.x;
  __shared__ float t[64][65];
  if (b >= 5536) {  // ---- embedding + sinusoidal PE + layernorm ----
    int lane = threadIdx.x & 63, wave = threadIdx.x >> 6;
    int row = (b - 5536) * 4 + wave;
    int id = ids[row];
    float v[8];
#pragma unroll
    for (int i = 0; i < 8; ++i) {
      int c = lane + i * 64;
      float tk = emb[(size_t)id * 512 + c];
      int dp = c & ~1;
      float dv = expf((float)dp * (-9.210340371976184f / 512.0f));
      float ang = (float)row * dv;
      float pe = (c & 1) ? cosf(ang) : sinf(ang);
      v[i] = tk + pe;
      x[(size_t)row * 512 + c] = v[i];
    }
    float s = 0.f;
#pragma unroll
    for (int i = 0; i < 8; ++i) s += v[i];
#pragma unroll
    for (int m = 32; m; m >>= 1) s += __shfl_xor(s, m, 64);
    float mu = s * (1.0f / 512.0f);
    float var = 0.f;
#pragma unroll
    for (int i = 0; i < 8; ++i) { float d = v[i] - mu; var += d * d; }
#pragma unroll
    for (int m = 32; m; m >>= 1) var += __shfl_xor(var, m, 64);
    float rs = rsqrtf(var * (1.0f / 512.0f) + 1e-5f);
    u16* orow = xn + (size_t)row * 512;
#pragma unroll
    for (int i = 0; i < 8; ++i) {
      int c = lane + i * 64;
      orow[c] = f2bf((v[i] - mu) * rs * sc[c] + bi[c]);
    }
    return;
  }
  // ---- weight transpose f32 [K][N] -> bf16 [N][K] ----
  const float* in; u16* out; int K, N, nx, ky;
  if (b < 384)       { int z = b / 192, r = b % 192; nx = r % 24; ky = r / 24;
                       in = qkvw + (size_t)z * 786432; out = wq_t + (size_t)z * 786432; N = 1536; K = 512; }
  else if (b < 512)  { int tt = b - 384, z = tt / 64, r = tt % 64; nx = r % 8; ky = r / 8;
                       in = outw + (size_t)z * 262144; out = wo_t + (size_t)z * 262144; N = 512; K = 512; }
  else if (b < 1024) { int tt = b - 512, z = tt / 256, r = tt % 256; nx = r % 32; ky = r / 32;
                       in = w1 + (size_t)z * 1048576; out = w1_t + (size_t)z * 1048576; N = 2048; K = 512; }
  else if (b < 1536) { int tt = b - 1024, z = tt / 256, r = tt % 256; nx = r % 8; ky = r / 8;
                       in = w2 + (size_t)z * 1048576; out = w2_t + (size_t)z * 1048576; N = 512; K = 2048; }
  else               { int tt = b - 1536; nx = tt % 500; ky = tt / 500;
                       in = hw; out = wh_t; N = 32000; K = 512; }
  int n0 = nx * 64, k0 = ky * 64;
  for (int e = threadIdx.x; e < 4096; e += 256) {
    int r = e >> 6, c = e & 63;
    t[r][c] = in[(size_t)(k0 + r) * N + n0 + c];
  }
  __syncthreads();
  for (int e = threadIdx.x; e < 4096; e += 256) {
    int r = e >> 6, c = e & 63;
    out[(size_t)(n0 + r) * K + k0 + c] = f2bf(t[c][r]);
  }
}

// ---------------- fused split-K reduce (bf16 partials) + residual + layernorm ----------------
__global__ __launch_bounds__(256) void reduce_ln(const u16* __restrict__ part, int nz,
    const float* __restrict__ bias, float* __restrict__ x,
    const float* __restrict__ sc, const float* __restrict__ bi, u16* __restrict__ xn) {
  int lane = threadIdx.x & 63, wave = threadIdx.x >> 6;
  int row = blockIdx.x * 4 + wave;
  float* xr = x + (size_t)row * 512;
  float v[8];
#pragma unroll
  for (int i = 0; i < 8; ++i) v[i] = xr[lane + i * 64];
  if (bias) {
#pragma unroll
    for (int i = 0; i < 8; ++i) v[i] += bias[lane + i * 64];
  }
  for (int z = 0; z < nz; ++z) {
    const u16* pz = part + (size_t)z * 1048576 + (size_t)row * 512;
#pragma unroll
    for (int i = 0; i < 8; ++i) v[i] += bf2f(pz[lane + i * 64]);
  }
#pragma unroll
  for (int i = 0; i < 8; ++i) xr[lane + i * 64] = v[i];
  float s = 0.f;
#pragma unroll
  for (int i = 0; i < 8; ++i) s += v[i];
#pragma unroll
  for (int m = 32; m; m >>= 1) s += __shfl_xor(s, m, 64);
  float mu = s * (1.0f / 512.0f);
  float var = 0.f;
#pragma unroll
  for (int i = 0; i < 8; ++i) { float d = v[i] - mu; var += d * d; }
#pragma unroll
  for (int m = 32; m; m >>= 1) var += __shfl_xor(var, m, 64);
  float rs = rsqrtf(var * (1.0f / 512.0f) + 1e-5f);
  u16* orow = xn + (size_t)row * 512;
#pragma unroll
  for (int i = 0; i < 8; ++i) {
    int c = lane + i * 64;
    orow[c] = f2bf((v[i] - mu) * rs * sc[c] + bi[c]);
  }
}

// ---------------- intra-chunk causal linear attention + chunk sums (MFMA) ----------------
// numer is stored bf16 (consumer re-accumulates in f32).
__global__ __launch_bounds__(256) void attn_intra(const u16* __restrict__ pq,
    const u16* __restrict__ pk, const u16* __restrict__ pv,
    u16* __restrict__ numer, float* __restrict__ denom,
    float* __restrict__ KVc, float* __restrict__ Ksc) {
  int c = blockIdx.x, h = blockIdx.y;
  int s0 = c * 128;
  __shared__ u16 kl[128 * 72];
  __shared__ u16 vl[128 * 72];
  __shared__ u16 kT[64 * 136];
  __shared__ u16 vT[64 * 136];
  __shared__ u16 P[128 * 136];
  int tid = threadIdx.x, lane = tid & 63, w = tid >> 6;
  int fr = lane & 15, kb = lane >> 4, rg = lane >> 4;
  const size_t base = ((size_t)h * 2048 + s0) * 64;

  for (int e = tid; e < 1024; e += 256) {
    int r = e >> 3, c8 = (e & 7) * 8;
    *(bf16x8*)&kl[r * 72 + c8] = *(const bf16x8*)&pk[base + r * 64 + c8];
    *(bf16x8*)&vl[r * 72 + c8] = *(const bf16x8*)&pv[base + r * 64 + c8];
  }
  int fiA = w, fiB = 7 - w;
  const u16* qA = pq + base + (size_t)(fiA * 16 + fr) * 64 + kb * 8;
  const u16* qB = pq + base + (size_t)(fiB * 16 + fr) * 64 + kb * 8;
  bf16x8 aQ0a = *(const bf16x8*)qA, aQ1a = *(const bf16x8*)(qA + 32);
  bf16x8 aQ0b = *(const bf16x8*)qB, aQ1b = *(const bf16x8*)(qB + 32);
  __syncthreads();

  {
    int dh = tid & 63, sb = tid >> 6;
#pragma unroll
    for (int b8 = 0; b8 < 4; ++b8) {
      int sbase = sb * 32 + b8 * 8;
      u16 tk[8], tv[8];
#pragma unroll
      for (int j = 0; j < 8; ++j) {
        tk[j] = kl[(sbase + j) * 72 + dh];
        tv[j] = vl[(sbase + j) * 72 + dh];
      }
      *(int4*)&kT[dh * 136 + sbase] = *(const int4*)tk;
      *(int4*)&vT[dh * 136 + sbase] = *(const int4*)tv;
    }
  }

#pragma unroll
  for (int ph = 0; ph < 2; ++ph) {
    int fi = ph ? fiB : fiA;
    bf16x8 aQ0 = ph ? aQ0b : aQ0a, aQ1 = ph ? aQ1b : aQ1a;
    f32x4 dsum = {0.f, 0.f, 0.f, 0.f};
    for (int fj = 0; fj <= fi; ++fj) {
      f32x4 s4 = {0.f, 0.f, 0.f, 0.f};
      bf16x8 b0 = *(const bf16x8*)&kl[(fj * 16 + fr) * 72 + kb * 8];
      bf16x8 b1 = *(const bf16x8*)&kl[(fj * 16 + fr) * 72 + kb * 8 + 32];
      s4 = __builtin_amdgcn_mfma_f32_16x16x32_bf16(aQ0, b0, s4, 0, 0, 0);
      s4 = __builtin_amdgcn_mfma_f32_16x16x32_bf16(aQ1, b1, s4, 0, 0, 0);
      int colL = fj * 16 + fr;
#pragma unroll
      for (int rr = 0; rr < 4; ++rr) {
        int rowL = fi * 16 + rg * 4 + rr;
        float mv = (colL <= rowL) ? s4[rr] : 0.f;
        dsum[rr] += mv;
        P[rowL * 136 + colL] = f2bf(mv);
      }
    }
    if ((fi & 1) == 0) {
      int colL = (fi + 1) * 16 + fr;
#pragma unroll
      for (int rr = 0; rr < 4; ++rr) P[(fi * 16 + rg * 4 + rr) * 136 + colL] = 0;
    }
#pragma unroll
    for (int rr = 0; rr < 4; ++rr) {
      float v = dsum[rr];
      v += __shfl_xor(v, 1, 16); v += __shfl_xor(v, 2, 16);
      v += __shfl_xor(v, 4, 16); v += __shfl_xor(v, 8, 16);
      if (fr == 0) denom[(size_t)h * 2048 + s0 + fi * 16 + rg * 4 + rr] = v;
    }
  }
  __syncthreads();

#pragma unroll
  for (int ph = 0; ph < 2; ++ph) {
    int fi = ph ? fiB : fiA;
    int ktmax = (fi + 2) >> 1;
    f32x4 o0 = {0,0,0,0}, o1 = {0,0,0,0}, o2 = {0,0,0,0}, o3 = {0,0,0,0};
    for (int kt = 0; kt < ktmax; ++kt) {
      bf16x8 aP = *(const bf16x8*)&P[(fi * 16 + fr) * 136 + kt * 32 + kb * 8];
      o0 = __builtin_amdgcn_mfma_f32_16x16x32_bf16(aP, *(const bf16x8*)&vT[(0 * 16 + fr) * 136 + kt * 32 + kb * 8], o0, 0, 0, 0);
      o1 = __builtin_amdgcn_mfma_f32_16x16x32_bf16(aP, *(const bf16x8*)&vT[(1 * 16 + fr) * 136 + kt * 32 + kb * 8], o1, 0, 0, 0);
      o2 = __builtin_amdgcn_mfma_f32_16x16x32_bf16(aP, *(const bf16x8*)&vT[(2 * 16 + fr) * 136 + kt * 32 + kb * 8], o2, 0, 0, 0);
      o3 = __builtin_amdgcn_mfma_f32_16x16x32_bf16(aP, *(const bf16x8*)&vT[(3 * 16 + fr) * 136 + kt * 32 + kb * 8], o3, 0, 0, 0);
    }
#pragma unroll
    for (int rr = 0; rr < 4; ++rr) {
      size_t rb = base + (size_t)(fi * 16 + rg * 4 + rr) * 64;
      numer[rb + 0 + fr]  = f2bf(o0[rr]);
      numer[rb + 16 + fr] = f2bf(o1[rr]);
      numer[rb + 32 + fr] = f2bf(o2[rr]);
      numer[rb + 48 + fr] = f2bf(o3[rr]);
    }
  }

  {
    f32x4 k0 = {0,0,0,0}, k1 = {0,0,0,0}, k2 = {0,0,0,0}, k3 = {0,0,0,0};
    for (int kt = 0; kt < 4; ++kt) {
      bf16x8 aK = *(const bf16x8*)&kT[(w * 16 + fr) * 136 + kt * 32 + kb * 8];
      k0 = __builtin_amdgcn_mfma_f32_16x16x32_bf16(aK, *(const bf16x8*)&vT[(0 * 16 + fr) * 136 + kt * 32 + kb * 8], k0, 0, 0, 0);
      k1 = __builtin_amdgcn_mfma_f32_16x16x32_bf16(aK, *(const bf16x8*)&vT[(1 * 16 + fr) * 136 + kt * 32 + kb * 8], k1, 0, 0, 0);
      k2 = __builtin_amdgcn_mfma_f32_16x16x32_bf16(aK, *(const bf16x8*)&vT[(2 * 16 + fr) * 136 + kt * 32 + kb * 8], k2, 0, 0, 0);
      k3 = __builtin_amdgcn_mfma_f32_16x16x32_bf16(aK, *(const bf16x8*)&vT[(3 * 16 + fr) * 136 + kt * 32 + kb * 8], k3, 0, 0, 0);
    }
    float* kvb = KVc + ((size_t)h * 16 + c) * 4096;
#pragma unroll
    for (int rr = 0; rr < 4; ++rr) {
      int row = w * 16 + rg * 4 + rr;
      kvb[row * 64 + 0 + fr]  = k0[rr];
      kvb[row * 64 + 16 + fr] = k1[rr];
      kvb[row * 64 + 32 + fr] = k2[rr];
      kvb[row * 64 + 48 + fr] = k3[rr];
    }
  }
  if (tid < 64) {
    float s = 0.f;
    for (int t8 = 0; t8 < 16; ++t8) {
      bf16x8 kv = *(const bf16x8*)&kT[tid * 136 + t8 * 8];
#pragma unroll
      for (int tt = 0; tt < 8; ++tt) s += bf2f(((const u16*)&kv)[tt]);
    }
    Ksc[((size_t)h * 16 + c) * 64 + tid] = s;
  }
}

// ---------------- inter-chunk prefix + finalize (bf16 numer in) ----------------
__global__ __launch_bounds__(256) void attn_inter(const u16* __restrict__ pq,
    const u16* __restrict__ numer, const float* __restrict__ denom,
    const float* __restrict__ KVc, const float* __restrict__ Ksc,
    u16* __restrict__ attn) {
  int c = blockIdx.x, h = blockIdx.y;
  int s0 = c * 128;
  __shared__ float KVp[4096];
  __shared__ float Kp[64];
  __shared__ float ql[128 * 65];
  int tid = threadIdx.x;
  for (int e = tid; e < 1024; e += 256) {
    f32x4 a = {0.f, 0.f, 0.f, 0.f};
    for (int cp = 0; cp < c; ++cp)
      a += *(const f32x4*)&KVc[((size_t)h * 16 + cp) * 4096 + e * 4];
    *(f32x4*)&KVp[e * 4] = a;
  }
  if (tid < 64) {
    float a = 0.f;
    for (int cp = 0; cp < c; ++cp) a += Ksc[((size_t)h * 16 + cp) * 64 + tid];
    Kp[tid] = a;
  }
  for (int e = tid; e < 1024; e += 256) {
    bf16x8 q8 = *(const bf16x8*)&pq[((size_t)h * 2048 + s0) * 64 + e * 8];
    int row = e >> 3, cb = (e & 7) * 8;
#pragma unroll
    for (int tt = 0; tt < 8; ++tt) ql[row * 65 + cb + tt] = bf2f(((const u16*)&q8)[tt]);
  }
  __syncthreads();
  int s = tid >> 1, half = tid & 1;
  float num[32];
  {
    const u16* np_ = numer + ((size_t)h * 2048 + s0 + s) * 64 + half * 32;
#pragma unroll
    for (int i = 0; i < 4; ++i) {
      bf16x8 n8 = *(const bf16x8*)&np_[i * 8];
#pragma unroll
      for (int tt = 0; tt < 8; ++tt) num[i * 8 + tt] = bf2f(((const u16*)&n8)[tt]);
    }
  }
  float den = denom[(size_t)h * 2048 + s0 + s] + 1e-6f;
  for (int i = 0; i < 64; ++i) {
    float qv = ql[s * 65 + i];
    den += qv * Kp[i];
    const f32x4* kv = (const f32x4*)&KVp[i * 64 + half * 32];
#pragma unroll
    for (int j4 = 0; j4 < 8; ++j4) {
      f32x4 kvv = kv[j4];
#pragma unroll
      for (int t = 0; t < 4; ++t) num[j4 * 4 + t] += qv * kvv[t];
    }
  }
  float inv = 1.f / den;
  u16* op = attn + (size_t)(s0 + s) * 512 + h * 64 + half * 32;
#pragma unroll
  for (int j = 0; j < 32; ++j) op[j] = f2bf(num[j] * inv);
}

// ---------------- 128x128 pipelined bf16 GEMM: C = A[M][K] * Bt[N][K]^T ----------------
// EPI: 2 = bias+gelu->bf16; 4 = phi(qkv)->bf16; 5 = split-K partial (bf16!)
template <int EPI>
__global__ __launch_bounds__(512, 2) void gemm_bt(const u16* __restrict__ A,
    const u16* __restrict__ B, float* __restrict__ outF, u16* __restrict__ outB,
    const float* __restrict__ bias, int M, int N, int K, int Ksplit) {
  __shared__ u16 lds[32768];  // A:[2][8192] | B at 16384:[2][8192]
  int tid = threadIdx.x, lane = tid & 63, w = tid >> 6;
  int f = blockIdx.x + gridDim.x * blockIdx.y;
  int m0 = (f & 15) << 7, n0 = (f >> 4) << 7;
  int wr = w >> 2, wc = w & 3;
  int fr = lane & 15, kb = lane >> 4;
  int z = blockIdx.z;
  int kbeg = z * Ksplit;
  int KT = Ksplit >> 6;

  auto stage = [&](int d, int u, int k0) {
    int t = u & 1;
    int row = t * 64 + w * 8 + (lane >> 3);
    int slot = (lane & 7) ^ ((lane >> 3) & 7);
    const u16* g = (u < 2 ? A + (size_t)(m0 + row) * K : B + (size_t)(n0 + row) * K)
                   + k0 + slot * 8;
    int dst = (u < 2 ? d * 8192 : 16384 + d * 8192) + t * 4096 + w * 512;
    load16(g, &lds[dst]);
  };
  auto rdA = [&](int d, int i, int kk) {
    int row = wr * 64 + i * 16 + fr;
    return *(const bf16x8*)&lds[d * 8192 + row * 64 + ((((kk << 2) | kb) ^ (fr & 7)) << 3)];
  };
  auto rdB = [&](int d, int j, int kk) {
    int row = wc * 32 + j * 16 + fr;
    return *(const bf16x8*)&lds[16384 + d * 8192 + row * 64 + ((((kk << 2) | kb) ^ (fr & 7)) << 3)];
  };

  f32x4 acc[4][2];
#pragma unroll
  for (int i = 0; i < 4; ++i)
#pragma unroll
    for (int j = 0; j < 2; ++j) acc[i][j] = (f32x4){0.f, 0.f, 0.f, 0.f};

#pragma unroll 1
  for (int u = 0; u < 4; ++u) stage(0, u, kbeg);
  __syncthreads();

  for (int t = 0; t < KT; ++t) {
    int d = t & 1, e = d ^ 1;
    int k1 = kbeg + ((t + 1) << 6);
    bool pre = (t + 1) < KT;
    bf16x8 aF[4], bF[2];
    if (pre) { stage(e, 0, k1); stage(e, 1, k1); }
#pragma unroll
    for (int i = 0; i < 4; ++i) aF[i] = rdA(d, i, 0);
#pragma unroll
    for (int j = 0; j < 2; ++j) bF[j] = rdB(d, j, 0);
    __builtin_amdgcn_s_setprio(1);
#pragma unroll
    for (int i = 0; i < 4; ++i)
#pragma unroll
      for (int j = 0; j < 2; ++j)
        acc[i][j] = __builtin_amdgcn_mfma_f32_16x16x32_bf16(aF[i], bF[j], acc[i][j], 0, 0, 0);
    __builtin_amdgcn_s_setprio(0);
    __builtin_amdgcn_sched_barrier(0);
    if (pre) { stage(e, 2, k1); stage(e, 3, k1); }
#pragma unroll
    for (int i = 0; i < 4; ++i) aF[i] = rdA(d, i, 1);
#pragma unroll
    for (int j = 0; j < 2; ++j) bF[j] = rdB(d, j, 1);
    __builtin_amdgcn_s_setprio(1);
#pragma unroll
    for (int i = 0; i < 4; ++i)
#pragma unroll
      for (int j = 0; j < 2; ++j)
        acc[i][j] = __builtin_amdgcn_mfma_f32_16x16x32_bf16(aF[i], bF[j], acc[i][j], 0, 0, 0);
    __builtin_amdgcn_s_setprio(0);
    __syncthreads();
  }

  int rq = lane >> 4;
#pragma unroll
  for (int i = 0; i < 4; ++i) {
#pragma unroll
    for (int j = 0; j < 2; ++j) {
      int col = n0 + wc * 32 + j * 16 + fr;
#pragma unroll
      for (int r = 0; r < 4; ++r) {
        int row = m0 + wr * 64 + i * 16 + rq * 4 + r;
        size_t o = (size_t)row * N + col;
        float vacc = acc[i][j][r];
        if (EPI == 2) {
          float t = vacc + bias[col];
          outB[o] = f2bf(0.5f * t * (1.f + erff(t * 0.70710678118654752f)));
        } else if (EPI == 4) {
          int part = col >> 9, d = col & 511, h = d >> 6, dh = d & 63;
          float wv = (part == 2) ? vacc : (vacc > 0.f ? vacc + 1.f : expf(vacc));
          outB[(size_t)part * 1048576 + (((size_t)h * 2048 + row) * 64 + dh)] = f2bf(wv);
        } else {  // 5: bf16 split-K partial
          outB[(size_t)z * 1048576 + o] = f2bf(vacc);
        }
      }
    }
  }
}

// ---------------- 256x256 pipelined bf16 GEMM (head) ----------------
__global__ __launch_bounds__(512, 2) void gemm256(const u16* __restrict__ A,
    const u16* __restrict__ B, float* __restrict__ C, int M, int N, int K) {
  __shared__ u16 lds[65536];  // [A0|A1|B0|B1] each 16384 u16
  int tid = threadIdx.x, lane = tid & 63, w = tid >> 6;
  int f = blockIdx.x;
  {
    int nwg = gridDim.x;
    int q = nwg >> 3;              // nwg % 8 == 0 required
    f = (f & 7) * q + (f >> 3);    // XCD-contiguous chunks
  }
  int m0 = (f & 7) << 8;           // m fastest for B-panel L2 reuse
  int n0 = (f >> 3) << 8;
  int wr = w >> 2, wc = w & 3;
  int fr = lane & 15, kb = lane >> 4;

  auto stage = [&](int d, int u, int k0) {
    int us = u & 3;
    int row = us * 64 + w * 8 + (lane >> 3);
    int slot = (lane & 7) ^ ((lane >> 3) & 7);
    const u16* g = (u < 4 ? A + (size_t)(m0 + row) * K : B + (size_t)(n0 + row) * K)
                   + k0 + slot * 8;
    int dst = (u < 4 ? d * 16384 : 32768 + d * 16384) + us * 4096 + w * 512;
    load16(g, &lds[dst]);
  };
  auto rdA = [&](int d, int i, int kk) {
    int row = wr * 128 + i * 16 + fr;
    return *(const bf16x8*)&lds[d * 16384 + row * 64 + ((((kk << 2) | kb) ^ (fr & 7)) << 3)];
  };
  auto rdB = [&](int d, int j, int kk) {
    int row = wc * 64 + j * 16 + fr;
    return *(const bf16x8*)&lds[32768 + d * 16384 + row * 64 + ((((kk << 2) | kb) ^ (fr & 7)) << 3)];
  };

  f32x4 acc[8][4];
#pragma unroll
  for (int i = 0; i < 8; ++i)
#pragma unroll
    for (int j = 0; j < 4; ++j) acc[i][j] = (f32x4){0.f, 0.f, 0.f, 0.f};

  int KT = K >> 6;
#pragma unroll 1
  for (int u = 0; u < 8; ++u) stage(0, u, 0);
  __syncthreads();

  for (int t = 0; t < KT; ++t) {
    int d = t & 1, e = d ^ 1;
    int k1 = (t + 1) << 6;
    bool pre = (t + 1) < KT;
    bf16x8 aF[4][2], bF[4][2];
    if (pre) { stage(e, 0, k1); stage(e, 1, k1); }
#pragma unroll
    for (int i = 0; i < 4; ++i) { aF[i][0] = rdA(d, i, 0); aF[i][1] = rdA(d, i, 1); }
#pragma unroll
    for (int j = 0; j < 2; ++j) { bF[j][0] = rdB(d, j, 0); bF[j][1] = rdB(d, j, 1); }
    __builtin_amdgcn_s_setprio(1);
#pragma unroll
    for (int i = 0; i < 4; ++i)
#pragma unroll
      for (int j = 0; j < 2; ++j)
#pragma unroll
        for (int kk = 0; kk < 2; ++kk)
          acc[i][j] = __builtin_amdgcn_mfma_f32_16x16x32_bf16(aF[i][kk], bF[j][kk], acc[i][j], 0, 0, 0);
    __builtin_amdgcn_s_setprio(0);
    __builtin_amdgcn_sched_barrier(0);
    if (pre) { stage(e, 2, k1); stage(e, 3, k1); }
#pragma unroll
    for (int j = 2; j < 4; ++j) { bF[j][0] = rdB(d, j, 0); bF[j][1] = rdB(d, j, 1); }
    __builtin_amdgcn_s_setprio(1);
#pragma unroll
    for (int i = 0; i < 4; ++i)
#pragma unroll
      for (int j = 2; j < 4; ++j)
#pragma unroll
        for (int kk = 0; kk < 2; ++kk)
          acc[i][j] = __builtin_amdgcn_mfma_f32_16x16x32_bf16(aF[i][kk], bF[j][kk], acc[i][j], 0, 0, 0);
    __builtin_amdgcn_s_setprio(0);
    __builtin_amdgcn_sched_barrier(0);
    if (pre) { stage(e, 4, k1); stage(e, 5, k1); }
#pragma unroll
    for (int i = 0; i < 4; ++i) { aF[i][0] = rdA(d, i + 4, 0); aF[i][1] = rdA(d, i + 4, 1); }
    __builtin_amdgcn_s_setprio(1);
#pragma unroll
    for (int i = 0; i < 4; ++i)
#pragma unroll
      for (int j = 0; j < 2; ++j)
#pragma unroll
        for (int kk = 0; kk < 2; ++kk)
          acc[i + 4][j] = __builtin_amdgcn_mfma_f32_16x16x32_bf16(aF[i][kk], bF[j][kk], acc[i + 4][j], 0, 0, 0);
    __builtin_amdgcn_s_setprio(0);
    __builtin_amdgcn_sched_barrier(0);
    if (pre) { stage(e, 6, k1); stage(e, 7, k1); }
    __builtin_amdgcn_s_setprio(1);
#pragma unroll
    for (int i = 0; i < 4; ++i)
#pragma unroll
      for (int j = 2; j < 4; ++j)
#pragma unroll
        for (int kk = 0; kk < 2; ++kk)
          acc[i + 4][j] = __builtin_amdgcn_mfma_f32_16x16x32_bf16(aF[i][kk], bF[j][kk], acc[i + 4][j], 0, 0, 0);
    __builtin_amdgcn_s_setprio(0);
    __syncthreads();
  }

  int rq = lane >> 4;
#pragma unroll
  for (int i = 0; i < 8; ++i) {
#pragma unroll
    for (int j = 0; j < 4; ++j) {
      int col = n0 + wc * 64 + j * 16 + fr;
#pragma unroll
      for (int r = 0; r < 4; ++r) {
        int row = m0 + wr * 128 + i * 16 + rq * 4 + r;
        C[(size_t)row * N + col] = acc[i][j][r];
      }
    }
  }
}

// ---------------- host launcher ----------------
extern "C" void kernel_launch(void* const* d_in, const int* in_sizes, int n_in,
                              void* d_out, int out_size, void* d_ws, size_t ws_size,
                              hipStream_t stream) {
  const int*   ids  = (const int*)d_in[0];
  const float* tok  = (const float*)d_in[1];
  const float* ln1s = (const float*)d_in[2];
  const float* ln1b = (const float*)d_in[3];
  const float* qkvw = (const float*)d_in[4];
  const float* outw = (const float*)d_in[5];
  const float* ln2s = (const float*)d_in[6];
  const float* ln2b = (const float*)d_in[7];
  const float* w1   = (const float*)d_in[8];
  const float* b1   = (const float*)d_in[9];
  const float* w2   = (const float*)d_in[10];
  const float* b2   = (const float*)d_in[11];
  const float* lnfs = (const float*)d_in[12];
  const float* lnfb = (const float*)d_in[13];
  const float* hw   = (const float*)d_in[14];
  float* out = (float*)d_out;

  char* ws = (char*)d_ws;
  size_t off = 0;
  auto carve = [&](size_t bytes) {
    char* p = ws + off;
    off = (off + bytes + 255) & ~(size_t)255;
    return p;
  };
  u16*   wq_t   = (u16*)carve(2ull * 1536 * 512 * 2);
  u16*   wo_t   = (u16*)carve(2ull * 512 * 512 * 2);
  u16*   w1_t   = (u16*)carve(2ull * 2048 * 512 * 2);
  u16*   w2_t   = (u16*)carve(2ull * 512 * 2048 * 2);
  u16*   wh_t   = (u16*)carve(32000ull * 512 * 2);
  float* x      = (float*)carve(2048ull * 512 * 4);
  u16*   xn     = (u16*)carve(2048ull * 512 * 2);
  u16*   phiAll = (u16*)carve(3ull * 8 * 2048 * 64 * 2);   // pq | pk | pv
  u16*   numer  = (u16*)carve(8ull * 2048 * 64 * 2);       // bf16 numer
  float* denom  = (float*)carve(8ull * 2048 * 4);
  float* KVc    = (float*)carve(8ull * 16 * 4096 * 4);
  float* Ksc    = (float*)carve(8ull * 16 * 64 * 4);
  u16*   attn   = (u16*)carve(2048ull * 512 * 2);
  u16*   hmid   = (u16*)carve(2048ull * 2048 * 2);
  u16*   part   = (u16*)carve(4ull * 2048 * 512 * 2);      // bf16 split-K partials
  (void)ws_size; (void)in_sizes; (void)n_in; (void)out_size;

  u16* phiq = phiAll;
  u16* phik = phiAll + 1048576;
  u16* vbf  = phiAll + 2097152;

  prep_kernel<<<6048, 256, 0, stream>>>(qkvw, outw, w1, w2, hw,
                                        wq_t, wo_t, w1_t, w2_t, wh_t,
                                        ids, tok, ln1s, ln1b, x, xn);

  for (int l = 0; l < 2; ++l) {
    const u16* wq_l = wq_t + (size_t)l * 1536 * 512;
    const u16* wo_l = wo_t + (size_t)l * 512 * 512;
    const u16* w1_l = w1_t + (size_t)l * 2048 * 512;
    const u16* w2_l = w2_t + (size_t)l * 512 * 2048;
    const float* nls = (l == 0) ? ln1s + 512 : lnfs;
    const float* nlb = (l == 0) ? ln1b + 512 : lnfb;

    gemm_bt<4><<<dim3(12, 16), 512, 0, stream>>>(xn, wq_l, nullptr, phiAll, nullptr,
                                                 2048, 1536, 512, 512);
    attn_intra<<<dim3(16, 8), 256, 0, stream>>>(phiq, phik, vbf, numer, denom, KVc, Ksc);
    attn_inter<<<dim3(16, 8), 256, 0, stream>>>(phiq, numer, denom, KVc, Ksc, attn);
    gemm_bt<5><<<dim3(4, 16, 2), 512, 0, stream>>>(attn, wo_l, nullptr, part, nullptr,
                                                   2048, 512, 512, 256);
    reduce_ln<<<512, 256, 0, stream>>>(part, 2, nullptr, x, ln2s + l * 512, ln2b + l * 512, xn);
    gemm_bt<2><<<dim3(16, 16), 512, 0, stream>>>(xn, w1_l, nullptr, hmid, b1 + l * 2048,
                                                 2048, 2048, 512, 512);
    gemm_bt<5><<<dim3(4, 16, 4), 512, 0, stream>>>(hmid, w2_l, nullptr, part, nullptr,
                                                   2048, 512, 2048, 512);
    reduce_ln<<<512, 256, 0, stream>>>(part, 4, b2 + l * 512, x, nls, nlb, xn);
  }

  gemm256<<<1000, 512, 0, stream>>>(xn, wh_t, out, 2048, 32000, 512);
}

// Round 14
// 294.830 us; speedup vs baseline: 2.8803x; 1.0209x over previous
//
#include <hip/hip_runtime.h>
#include <cstdint>

typedef unsigned short u16;
typedef __bf16 bf16x8 __attribute__((ext_vector_type(8)));
typedef float f32x4 __attribute__((ext_vector_type(4)));

#define DEV __device__ __forceinline__

DEV u16 f2bf(float f) {
  union { float f; unsigned u; } v; v.f = f;
  unsigned u = v.u;
  u += 0x7FFFu + ((u >> 16) & 1u);
  return (u16)(u >> 16);
}
DEV float bf2f(u16 u) {
  union { unsigned u; float f; } v; v.u = ((unsigned)u) << 16;
  return v.f;
}

// async global->LDS, 16B per lane; LDS dest must be wave-uniform base.
DEV void load16(const u16* g, u16* l) {
  __builtin_amdgcn_global_load_lds(
      (const __attribute__((address_space(1))) unsigned int*)(const void*)g,
      (__attribute__((address_space(3))) unsigned int*)l, 16, 0, 0);
}

// ---------------- prep: all weight transposes + embedding/PE/LN (one launch) ----------------
__global__ __launch_bounds__(256) void prep_kernel(
    const float* __restrict__ qkvw, const float* __restrict__ outw,
    const float* __restrict__ w1, const float* __restrict__ w2,
    const float* __restrict__ hw, u16* __restrict__ wq_t, u16* __restrict__ wo_t,
    u16* __restrict__ w1_t, u16* __restrict__ w2_t, u16* __restrict__ wh_t,
    const int* __restrict__ ids, const float* __restrict__ emb,
    const float* __restrict__ sc, const float* __restrict__ bi,
    float* __restrict__ x, u16* __restrict__ xn) {
  int b = blockIdx.x;
  __shared__ float t[64][65];
  if (b >= 5536) {  // ---- embedding + sinusoidal PE + layernorm ----
    int lane = threadIdx.x & 63, wave = threadIdx.x >> 6;
    int row = (b - 5536) * 4 + wave;
    int id = ids[row];
    float v[8];
#pragma unroll
    for (int i = 0; i < 8; ++i) {
      int c = lane + i * 64;
      float tk = emb[(size_t)id * 512 + c];
      int dp = c & ~1;
      float dv = expf((float)dp * (-9.210340371976184f / 512.0f));
      float ang = (float)row * dv;
      float pe = (c & 1) ? cosf(ang) : sinf(ang);
      v[i] = tk + pe;
      x[(size_t)row * 512 + c] = v[i];
    }
    float s = 0.f;
#pragma unroll
    for (int i = 0; i < 8; ++i) s += v[i];
#pragma unroll
    for (int m = 32; m; m >>= 1) s += __shfl_xor(s, m, 64);
    float mu = s * (1.0f / 512.0f);
    float var = 0.f;
#pragma unroll
    for (int i = 0; i < 8; ++i) { float d = v[i] - mu; var += d * d; }
#pragma unroll
    for (int m = 32; m; m >>= 1) var += __shfl_xor(var, m, 64);
    float rs = rsqrtf(var * (1.0f / 512.0f) + 1e-5f);
    u16* orow = xn + (size_t)row * 512;
#pragma unroll
    for (int i = 0; i < 8; ++i) {
      int c = lane + i * 64;
      orow[c] = f2bf((v[i] - mu) * rs * sc[c] + bi[c]);
    }
    return;
  }
  // ---- weight transpose f32 [K][N] -> bf16 [N][K] ----
  const float* in; u16* out; int K, N, nx, ky;
  if (b < 384)       { int z = b / 192, r = b % 192; nx = r % 24; ky = r / 24;
                       in = qkvw + (size_t)z * 786432; out = wq_t + (size_t)z * 786432; N = 1536; K = 512; }
  else if (b < 512)  { int tt = b - 384, z = tt / 64, r = tt % 64; nx = r % 8; ky = r / 8;
                       in = outw + (size_t)z * 262144; out = wo_t + (size_t)z * 262144; N = 512; K = 512; }
  else if (b < 1024) { int tt = b - 512, z = tt / 256, r = tt % 256; nx = r % 32; ky = r / 32;
                       in = w1 + (size_t)z * 1048576; out = w1_t + (size_t)z * 1048576; N = 2048; K = 512; }
  else if (b < 1536) { int tt = b - 1024, z = tt / 256, r = tt % 256; nx = r % 8; ky = r / 8;
                       in = w2 + (size_t)z * 1048576; out = w2_t + (size_t)z * 1048576; N = 512; K = 2048; }
  else               { int tt = b - 1536; nx = tt % 500; ky = tt / 500;
                       in = hw; out = wh_t; N = 32000; K = 512; }
  int n0 = nx * 64, k0 = ky * 64;
  for (int e = threadIdx.x; e < 4096; e += 256) {
    int r = e >> 6, c = e & 63;
    t[r][c] = in[(size_t)(k0 + r) * N + n0 + c];
  }
  __syncthreads();
  for (int e = threadIdx.x; e < 4096; e += 256) {
    int r = e >> 6, c = e & 63;
    out[(size_t)(n0 + r) * K + k0 + c] = f2bf(t[c][r]);
  }
}

// ---------------- fused split-K reduce (bf16 partials) + residual + layernorm ----------------
__global__ __launch_bounds__(256) void reduce_ln(const u16* __restrict__ part, int nz,
    const float* __restrict__ bias, float* __restrict__ x,
    const float* __restrict__ sc, const float* __restrict__ bi, u16* __restrict__ xn) {
  int lane = threadIdx.x & 63, wave = threadIdx.x >> 6;
  int row = blockIdx.x * 4 + wave;
  float* xr = x + (size_t)row * 512;
  float v[8];
#pragma unroll
  for (int i = 0; i < 8; ++i) v[i] = xr[lane + i * 64];
  if (bias) {
#pragma unroll
    for (int i = 0; i < 8; ++i) v[i] += bias[lane + i * 64];
  }
  for (int z = 0; z < nz; ++z) {
    const u16* pz = part + (size_t)z * 1048576 + (size_t)row * 512;
#pragma unroll
    for (int i = 0; i < 8; ++i) v[i] += bf2f(pz[lane + i * 64]);
  }
#pragma unroll
  for (int i = 0; i < 8; ++i) xr[lane + i * 64] = v[i];
  float s = 0.f;
#pragma unroll
  for (int i = 0; i < 8; ++i) s += v[i];
#pragma unroll
  for (int m = 32; m; m >>= 1) s += __shfl_xor(s, m, 64);
  float mu = s * (1.0f / 512.0f);
  float var = 0.f;
#pragma unroll
  for (int i = 0; i < 8; ++i) { float d = v[i] - mu; var += d * d; }
#pragma unroll
  for (int m = 32; m; m >>= 1) var += __shfl_xor(var, m, 64);
  float rs = rsqrtf(var * (1.0f / 512.0f) + 1e-5f);
  u16* orow = xn + (size_t)row * 512;
#pragma unroll
  for (int i = 0; i < 8; ++i) {
    int c = lane + i * 64;
    orow[c] = f2bf((v[i] - mu) * rs * sc[c] + bi[c]);
  }
}

// ---------------- intra-chunk causal linear attention + chunk sums (MFMA) ----------------
__global__ __launch_bounds__(256) void attn_intra(const u16* __restrict__ pq,
    const u16* __restrict__ pk, const u16* __restrict__ pv,
    u16* __restrict__ numer, float* __restrict__ denom,
    float* __restrict__ KVc, float* __restrict__ Ksc) {
  int c = blockIdx.x, h = blockIdx.y;
  int s0 = c * 128;
  __shared__ u16 kl[128 * 72];
  __shared__ u16 vl[128 * 72];
  __shared__ u16 kT[64 * 136];
  __shared__ u16 vT[64 * 136];
  __shared__ u16 P[128 * 136];
  int tid = threadIdx.x, lane = tid & 63, w = tid >> 6;
  int fr = lane & 15, kb = lane >> 4, rg = lane >> 4;
  const size_t base = ((size_t)h * 2048 + s0) * 64;

  for (int e = tid; e < 1024; e += 256) {
    int r = e >> 3, c8 = (e & 7) * 8;
    *(bf16x8*)&kl[r * 72 + c8] = *(const bf16x8*)&pk[base + r * 64 + c8];
    *(bf16x8*)&vl[r * 72 + c8] = *(const bf16x8*)&pv[base + r * 64 + c8];
  }
  int fiA = w, fiB = 7 - w;
  const u16* qA = pq + base + (size_t)(fiA * 16 + fr) * 64 + kb * 8;
  const u16* qB = pq + base + (size_t)(fiB * 16 + fr) * 64 + kb * 8;
  bf16x8 aQ0a = *(const bf16x8*)qA, aQ1a = *(const bf16x8*)(qA + 32);
  bf16x8 aQ0b = *(const bf16x8*)qB, aQ1b = *(const bf16x8*)(qB + 32);
  __syncthreads();

  {
    int dh = tid & 63, sb = tid >> 6;
#pragma unroll
    for (int b8 = 0; b8 < 4; ++b8) {
      int sbase = sb * 32 + b8 * 8;
      u16 tk[8], tv[8];
#pragma unroll
      for (int j = 0; j < 8; ++j) {
        tk[j] = kl[(sbase + j) * 72 + dh];
        tv[j] = vl[(sbase + j) * 72 + dh];
      }
      *(int4*)&kT[dh * 136 + sbase] = *(const int4*)tk;
      *(int4*)&vT[dh * 136 + sbase] = *(const int4*)tv;
    }
  }

#pragma unroll
  for (int ph = 0; ph < 2; ++ph) {
    int fi = ph ? fiB : fiA;
    bf16x8 aQ0 = ph ? aQ0b : aQ0a, aQ1 = ph ? aQ1b : aQ1a;
    f32x4 dsum = {0.f, 0.f, 0.f, 0.f};
    for (int fj = 0; fj <= fi; ++fj) {
      f32x4 s4 = {0.f, 0.f, 0.f, 0.f};
      bf16x8 b0 = *(const bf16x8*)&kl[(fj * 16 + fr) * 72 + kb * 8];
      bf16x8 b1 = *(const bf16x8*)&kl[(fj * 16 + fr) * 72 + kb * 8 + 32];
      s4 = __builtin_amdgcn_mfma_f32_16x16x32_bf16(aQ0, b0, s4, 0, 0, 0);
      s4 = __builtin_amdgcn_mfma_f32_16x16x32_bf16(aQ1, b1, s4, 0, 0, 0);
      int colL = fj * 16 + fr;
#pragma unroll
      for (int rr = 0; rr < 4; ++rr) {
        int rowL = fi * 16 + rg * 4 + rr;
        float mv = (colL <= rowL) ? s4[rr] : 0.f;
        dsum[rr] += mv;
        P[rowL * 136 + colL] = f2bf(mv);
      }
    }
    if ((fi & 1) == 0) {
      int colL = (fi + 1) * 16 + fr;
#pragma unroll
      for (int rr = 0; rr < 4; ++rr) P[(fi * 16 + rg * 4 + rr) * 136 + colL] = 0;
    }
#pragma unroll
    for (int rr = 0; rr < 4; ++rr) {
      float v = dsum[rr];
      v += __shfl_xor(v, 1, 16); v += __shfl_xor(v, 2, 16);
      v += __shfl_xor(v, 4, 16); v += __shfl_xor(v, 8, 16);
      if (fr == 0) denom[(size_t)h * 2048 + s0 + fi * 16 + rg * 4 + rr] = v;
    }
  }
  __syncthreads();

#pragma unroll
  for (int ph = 0; ph < 2; ++ph) {
    int fi = ph ? fiB : fiA;
    int ktmax = (fi + 2) >> 1;
    f32x4 o0 = {0,0,0,0}, o1 = {0,0,0,0}, o2 = {0,0,0,0}, o3 = {0,0,0,0};
    for (int kt = 0; kt < ktmax; ++kt) {
      bf16x8 aP = *(const bf16x8*)&P[(fi * 16 + fr) * 136 + kt * 32 + kb * 8];
      o0 = __builtin_amdgcn_mfma_f32_16x16x32_bf16(aP, *(const bf16x8*)&vT[(0 * 16 + fr) * 136 + kt * 32 + kb * 8], o0, 0, 0, 0);
      o1 = __builtin_amdgcn_mfma_f32_16x16x32_bf16(aP, *(const bf16x8*)&vT[(1 * 16 + fr) * 136 + kt * 32 + kb * 8], o1, 0, 0, 0);
      o2 = __builtin_amdgcn_mfma_f32_16x16x32_bf16(aP, *(const bf16x8*)&vT[(2 * 16 + fr) * 136 + kt * 32 + kb * 8], o2, 0, 0, 0);
      o3 = __builtin_amdgcn_mfma_f32_16x16x32_bf16(aP, *(const bf16x8*)&vT[(3 * 16 + fr) * 136 + kt * 32 + kb * 8], o3, 0, 0, 0);
    }
#pragma unroll
    for (int rr = 0; rr < 4; ++rr) {
      size_t rb = base + (size_t)(fi * 16 + rg * 4 + rr) * 64;
      numer[rb + 0 + fr]  = f2bf(o0[rr]);
      numer[rb + 16 + fr] = f2bf(o1[rr]);
      numer[rb + 32 + fr] = f2bf(o2[rr]);
      numer[rb + 48 + fr] = f2bf(o3[rr]);
    }
  }

  {
    f32x4 k0 = {0,0,0,0}, k1 = {0,0,0,0}, k2 = {0,0,0,0}, k3 = {0,0,0,0};
    for (int kt = 0; kt < 4; ++kt) {
      bf16x8 aK = *(const bf16x8*)&kT[(w * 16 + fr) * 136 + kt * 32 + kb * 8];
      k0 = __builtin_amdgcn_mfma_f32_16x16x32_bf16(aK, *(const bf16x8*)&vT[(0 * 16 + fr) * 136 + kt * 32 + kb * 8], k0, 0, 0, 0);
      k1 = __builtin_amdgcn_mfma_f32_16x16x32_bf16(aK, *(const bf16x8*)&vT[(1 * 16 + fr) * 136 + kt * 32 + kb * 8], k1, 0, 0, 0);
      k2 = __builtin_amdgcn_mfma_f32_16x16x32_bf16(aK, *(const bf16x8*)&vT[(2 * 16 + fr) * 136 + kt * 32 + kb * 8], k2, 0, 0, 0);
      k3 = __builtin_amdgcn_mfma_f32_16x16x32_bf16(aK, *(const bf16x8*)&vT[(3 * 16 + fr) * 136 + kt * 32 + kb * 8], k3, 0, 0, 0);
    }
    float* kvb = KVc + ((size_t)h * 16 + c) * 4096;
#pragma unroll
    for (int rr = 0; rr < 4; ++rr) {
      int row = w * 16 + rg * 4 + rr;
      kvb[row * 64 + 0 + fr]  = k0[rr];
      kvb[row * 64 + 16 + fr] = k1[rr];
      kvb[row * 64 + 32 + fr] = k2[rr];
      kvb[row * 64 + 48 + fr] = k3[rr];
    }
  }
  if (tid < 64) {
    float s = 0.f;
    for (int t8 = 0; t8 < 16; ++t8) {
      bf16x8 kv = *(const bf16x8*)&kT[tid * 136 + t8 * 8];
#pragma unroll
      for (int tt = 0; tt < 8; ++tt) s += bf2f(((const u16*)&kv)[tt]);
    }
    Ksc[((size_t)h * 16 + c) * 64 + tid] = s;
  }
}

// ---------------- inter-chunk prefix + finalize (bf16 numer in) ----------------
__global__ __launch_bounds__(256) void attn_inter(const u16* __restrict__ pq,
    const u16* __restrict__ numer, const float* __restrict__ denom,
    const float* __restrict__ KVc, const float* __restrict__ Ksc,
    u16* __restrict__ attn) {
  int c = blockIdx.x, h = blockIdx.y;
  int s0 = c * 128;
  __shared__ float KVp[4096];
  __shared__ float Kp[64];
  __shared__ float ql[128 * 65];
  int tid = threadIdx.x;
  for (int e = tid; e < 1024; e += 256) {
    f32x4 a = {0.f, 0.f, 0.f, 0.f};
    for (int cp = 0; cp < c; ++cp)
      a += *(const f32x4*)&KVc[((size_t)h * 16 + cp) * 4096 + e * 4];
    *(f32x4*)&KVp[e * 4] = a;
  }
  if (tid < 64) {
    float a = 0.f;
    for (int cp = 0; cp < c; ++cp) a += Ksc[((size_t)h * 16 + cp) * 64 + tid];
    Kp[tid] = a;
  }
  for (int e = tid; e < 1024; e += 256) {
    bf16x8 q8 = *(const bf16x8*)&pq[((size_t)h * 2048 + s0) * 64 + e * 8];
    int row = e >> 3, cb = (e & 7) * 8;
#pragma unroll
    for (int tt = 0; tt < 8; ++tt) ql[row * 65 + cb + tt] = bf2f(((const u16*)&q8)[tt]);
  }
  __syncthreads();
  int s = tid >> 1, half = tid & 1;
  float num[32];
  {
    const u16* np_ = numer + ((size_t)h * 2048 + s0 + s) * 64 + half * 32;
#pragma unroll
    for (int i = 0; i < 4; ++i) {
      bf16x8 n8 = *(const bf16x8*)&np_[i * 8];
#pragma unroll
      for (int tt = 0; tt < 8; ++tt) num[i * 8 + tt] = bf2f(((const u16*)&n8)[tt]);
    }
  }
  float den = denom[(size_t)h * 2048 + s0 + s] + 1e-6f;
  for (int i = 0; i < 64; ++i) {
    float qv = ql[s * 65 + i];
    den += qv * Kp[i];
    const f32x4* kv = (const f32x4*)&KVp[i * 64 + half * 32];
#pragma unroll
    for (int j4 = 0; j4 < 8; ++j4) {
      f32x4 kvv = kv[j4];
#pragma unroll
      for (int t = 0; t < 4; ++t) num[j4 * 4 + t] += qv * kvv[t];
    }
  }
  float inv = 1.f / den;
  u16* op = attn + (size_t)(s0 + s) * 512 + h * 64 + half * 32;
#pragma unroll
  for (int j = 0; j < 32; ++j) op[j] = f2bf(num[j] * inv);
}

// ---------------- 128x128 pipelined bf16 GEMM: C = A[M][K] * Bt[N][K]^T ----------------
// EPI: 2 = bias+gelu->bf16; 4 = phi(qkv)->bf16; 5 = split-K partial (bf16)
template <int EPI>
__global__ __launch_bounds__(512, 2) void gemm_bt(const u16* __restrict__ A,
    const u16* __restrict__ B, float* __restrict__ outF, u16* __restrict__ outB,
    const float* __restrict__ bias, int M, int N, int K, int Ksplit) {
  __shared__ u16 lds[32768];  // A:[2][8192] | B at 16384:[2][8192]
  int tid = threadIdx.x, lane = tid & 63, w = tid >> 6;
  int f = blockIdx.x + gridDim.x * blockIdx.y;
  int m0 = (f & 15) << 7, n0 = (f >> 4) << 7;
  int wr = w >> 2, wc = w & 3;
  int fr = lane & 15, kb = lane >> 4;
  int z = blockIdx.z;
  int kbeg = z * Ksplit;
  int KT = Ksplit >> 6;

  auto stage = [&](int d, int u, int k0) {
    int t = u & 1;
    int row = t * 64 + w * 8 + (lane >> 3);
    int slot = (lane & 7) ^ ((lane >> 3) & 7);
    const u16* g = (u < 2 ? A + (size_t)(m0 + row) * K : B + (size_t)(n0 + row) * K)
                   + k0 + slot * 8;
    int dst = (u < 2 ? d * 8192 : 16384 + d * 8192) + t * 4096 + w * 512;
    load16(g, &lds[dst]);
  };
  auto rdA = [&](int d, int i, int kk) {
    int row = wr * 64 + i * 16 + fr;
    return *(const bf16x8*)&lds[d * 8192 + row * 64 + ((((kk << 2) | kb) ^ (fr & 7)) << 3)];
  };
  auto rdB = [&](int d, int j, int kk) {
    int row = wc * 32 + j * 16 + fr;
    return *(const bf16x8*)&lds[16384 + d * 8192 + row * 64 + ((((kk << 2) | kb) ^ (fr & 7)) << 3)];
  };

  f32x4 acc[4][2];
#pragma unroll
  for (int i = 0; i < 4; ++i)
#pragma unroll
    for (int j = 0; j < 2; ++j) acc[i][j] = (f32x4){0.f, 0.f, 0.f, 0.f};

#pragma unroll 1
  for (int u = 0; u < 4; ++u) stage(0, u, kbeg);
  __syncthreads();

  for (int t = 0; t < KT; ++t) {
    int d = t & 1, e = d ^ 1;
    int k1 = kbeg + ((t + 1) << 6);
    bool pre = (t + 1) < KT;
    bf16x8 aF[4], bF[2];
    if (pre) { stage(e, 0, k1); stage(e, 1, k1); }
#pragma unroll
    for (int i = 0; i < 4; ++i) aF[i] = rdA(d, i, 0);
#pragma unroll
    for (int j = 0; j < 2; ++j) bF[j] = rdB(d, j, 0);
    __builtin_amdgcn_s_setprio(1);
#pragma unroll
    for (int i = 0; i < 4; ++i)
#pragma unroll
      for (int j = 0; j < 2; ++j)
        acc[i][j] = __builtin_amdgcn_mfma_f32_16x16x32_bf16(aF[i], bF[j], acc[i][j], 0, 0, 0);
    __builtin_amdgcn_s_setprio(0);
    __builtin_amdgcn_sched_barrier(0);
    if (pre) { stage(e, 2, k1); stage(e, 3, k1); }
#pragma unroll
    for (int i = 0; i < 4; ++i) aF[i] = rdA(d, i, 1);
#pragma unroll
    for (int j = 0; j < 2; ++j) bF[j] = rdB(d, j, 1);
    __builtin_amdgcn_s_setprio(1);
#pragma unroll
    for (int i = 0; i < 4; ++i)
#pragma unroll
      for (int j = 0; j < 2; ++j)
        acc[i][j] = __builtin_amdgcn_mfma_f32_16x16x32_bf16(aF[i], bF[j], acc[i][j], 0, 0, 0);
    __builtin_amdgcn_s_setprio(0);
    __syncthreads();
  }

  int rq = lane >> 4;
#pragma unroll
  for (int i = 0; i < 4; ++i) {
#pragma unroll
    for (int j = 0; j < 2; ++j) {
      int col = n0 + wc * 32 + j * 16 + fr;
#pragma unroll
      for (int r = 0; r < 4; ++r) {
        int row = m0 + wr * 64 + i * 16 + rq * 4 + r;
        size_t o = (size_t)row * N + col;
        float vacc = acc[i][j][r];
        if (EPI == 2) {
          float t = vacc + bias[col];
          outB[o] = f2bf(0.5f * t * (1.f + erff(t * 0.70710678118654752f)));
        } else if (EPI == 4) {
          int part = col >> 9, d = col & 511, h = d >> 6, dh = d & 63;
          float wv = (part == 2) ? vacc : (vacc > 0.f ? vacc + 1.f : expf(vacc));
          outB[(size_t)part * 1048576 + (((size_t)h * 2048 + row) * 64 + dh)] = f2bf(wv);
        } else {  // 5: bf16 split-K partial
          outB[(size_t)z * 1048576 + o] = f2bf(vacc);
        }
      }
    }
  }
}

// ---------------- 256x256 pipelined bf16 GEMM (head), nontemporal C-stores ----------------
__global__ __launch_bounds__(512, 2) void gemm256(const u16* __restrict__ A,
    const u16* __restrict__ B, float* __restrict__ C, int M, int N, int K) {
  __shared__ u16 lds[65536];  // [A0|A1|B0|B1] each 16384 u16
  int tid = threadIdx.x, lane = tid & 63, w = tid >> 6;
  int f = blockIdx.x;
  {
    int nwg = gridDim.x;
    int q = nwg >> 3;              // nwg % 8 == 0 required
    f = (f & 7) * q + (f >> 3);    // XCD-contiguous chunks
  }
  int m0 = (f & 7) << 8;           // m fastest for B-panel L2 reuse
  int n0 = (f >> 3) << 8;
  int wr = w >> 2, wc = w & 3;
  int fr = lane & 15, kb = lane >> 4;

  auto stage = [&](int d, int u, int k0) {
    int us = u & 3;
    int row = us * 64 + w * 8 + (lane >> 3);
    int slot = (lane & 7) ^ ((lane >> 3) & 7);
    const u16* g = (u < 4 ? A + (size_t)(m0 + row) * K : B + (size_t)(n0 + row) * K)
                   + k0 + slot * 8;
    int dst = (u < 4 ? d * 16384 : 32768 + d * 16384) + us * 4096 + w * 512;
    load16(g, &lds[dst]);
  };
  auto rdA = [&](int d, int i, int kk) {
    int row = wr * 128 + i * 16 + fr;
    return *(const bf16x8*)&lds[d * 16384 + row * 64 + ((((kk << 2) | kb) ^ (fr & 7)) << 3)];
  };
  auto rdB = [&](int d, int j, int kk) {
    int row = wc * 64 + j * 16 + fr;
    return *(const bf16x8*)&lds[32768 + d * 16384 + row * 64 + ((((kk << 2) | kb) ^ (fr & 7)) << 3)];
  };

  f32x4 acc[8][4];
#pragma unroll
  for (int i = 0; i < 8; ++i)
#pragma unroll
    for (int j = 0; j < 4; ++j) acc[i][j] = (f32x4){0.f, 0.f, 0.f, 0.f};

  int KT = K >> 6;
#pragma unroll 1
  for (int u = 0; u < 8; ++u) stage(0, u, 0);
  __syncthreads();

  for (int t = 0; t < KT; ++t) {
    int d = t & 1, e = d ^ 1;
    int k1 = (t + 1) << 6;
    bool pre = (t + 1) < KT;
    bf16x8 aF[4][2], bF[4][2];
    if (pre) { stage(e, 0, k1); stage(e, 1, k1); }
#pragma unroll
    for (int i = 0; i < 4; ++i) { aF[i][0] = rdA(d, i, 0); aF[i][1] = rdA(d, i, 1); }
#pragma unroll
    for (int j = 0; j < 2; ++j) { bF[j][0] = rdB(d, j, 0); bF[j][1] = rdB(d, j, 1); }
    __builtin_amdgcn_s_setprio(1);
#pragma unroll
    for (int i = 0; i < 4; ++i)
#pragma unroll
      for (int j = 0; j < 2; ++j)
#pragma unroll
        for (int kk = 0; kk < 2; ++kk)
          acc[i][j] = __builtin_amdgcn_mfma_f32_16x16x32_bf16(aF[i][kk], bF[j][kk], acc[i][j], 0, 0, 0);
    __builtin_amdgcn_s_setprio(0);
    __builtin_amdgcn_sched_barrier(0);
    if (pre) { stage(e, 2, k1); stage(e, 3, k1); }
#pragma unroll
    for (int j = 2; j < 4; ++j) { bF[j][0] = rdB(d, j, 0); bF[j][1] = rdB(d, j, 1); }
    __builtin_amdgcn_s_setprio(1);
#pragma unroll
    for (int i = 0; i < 4; ++i)
#pragma unroll
      for (int j = 2; j < 4; ++j)
#pragma unroll
        for (int kk = 0; kk < 2; ++kk)
          acc[i][j] = __builtin_amdgcn_mfma_f32_16x16x32_bf16(aF[i][kk], bF[j][kk], acc[i][j], 0, 0, 0);
    __builtin_amdgcn_s_setprio(0);
    __builtin_amdgcn_sched_barrier(0);
    if (pre) { stage(e, 4, k1); stage(e, 5, k1); }
#pragma unroll
    for (int i = 0; i < 4; ++i) { aF[i][0] = rdA(d, i + 4, 0); aF[i][1] = rdA(d, i + 4, 1); }
    __builtin_amdgcn_s_setprio(1);
#pragma unroll
    for (int i = 0; i < 4; ++i)
#pragma unroll
      for (int j = 0; j < 2; ++j)
#pragma unroll
        for (int kk = 0; kk < 2; ++kk)
          acc[i + 4][j] = __builtin_amdgcn_mfma_f32_16x16x32_bf16(aF[i][kk], bF[j][kk], acc[i + 4][j], 0, 0, 0);
    __builtin_amdgcn_s_setprio(0);
    __builtin_amdgcn_sched_barrier(0);
    if (pre) { stage(e, 6, k1); stage(e, 7, k1); }
    __builtin_amdgcn_s_setprio(1);
#pragma unroll
    for (int i = 0; i < 4; ++i)
#pragma unroll
      for (int j = 2; j < 4; ++j)
#pragma unroll
        for (int kk = 0; kk < 2; ++kk)
          acc[i + 4][j] = __builtin_amdgcn_mfma_f32_16x16x32_bf16(aF[i][kk], bF[j][kk], acc[i + 4][j], 0, 0, 0);
    __builtin_amdgcn_s_setprio(0);
    __syncthreads();
  }

  int rq = lane >> 4;
#pragma unroll
  for (int i = 0; i < 8; ++i) {
#pragma unroll
    for (int j = 0; j < 4; ++j) {
      int col = n0 + wc * 64 + j * 16 + fr;
#pragma unroll
      for (int r = 0; r < 4; ++r) {
        int row = m0 + wr * 128 + i * 16 + rq * 4 + r;
        __builtin_nontemporal_store(acc[i][j][r], &C[(size_t)row * N + col]);
      }
    }
  }
}

// ---------------- host launcher ----------------
extern "C" void kernel_launch(void* const* d_in, const int* in_sizes, int n_in,
                              void* d_out, int out_size, void* d_ws, size_t ws_size,
                              hipStream_t stream) {
  const int*   ids  = (const int*)d_in[0];
  const float* tok  = (const float*)d_in[1];
  const float* ln1s = (const float*)d_in[2];
  const float* ln1b = (const float*)d_in[3];
  const float* qkvw = (const float*)d_in[4];
  const float* outw = (const float*)d_in[5];
  const float* ln2s = (const float*)d_in[6];
  const float* ln2b = (const float*)d_in[7];
  const float* w1   = (const float*)d_in[8];
  const float* b1   = (const float*)d_in[9];
  const float* w2   = (const float*)d_in[10];
  const float* b2   = (const float*)d_in[11];
  const float* lnfs = (const float*)d_in[12];
  const float* lnfb = (const float*)d_in[13];
  const float* hw   = (const float*)d_in[14];
  float* out = (float*)d_out;

  char* ws = (char*)d_ws;
  size_t off = 0;
  auto carve = [&](size_t bytes) {
    char* p = ws + off;
    off = (off + bytes + 255) & ~(size_t)255;
    return p;
  };
  u16*   wq_t   = (u16*)carve(2ull * 1536 * 512 * 2);
  u16*   wo_t   = (u16*)carve(2ull * 512 * 512 * 2);
  u16*   w1_t   = (u16*)carve(2ull * 2048 * 512 * 2);
  u16*   w2_t   = (u16*)carve(2ull * 512 * 2048 * 2);
  u16*   wh_t   = (u16*)carve(32000ull * 512 * 2);
  float* x      = (float*)carve(2048ull * 512 * 4);
  u16*   xn     = (u16*)carve(2048ull * 512 * 2);
  u16*   phiAll = (u16*)carve(3ull * 8 * 2048 * 64 * 2);   // pq | pk | pv
  u16*   numer  = (u16*)carve(8ull * 2048 * 64 * 2);       // bf16 numer
  float* denom  = (float*)carve(8ull * 2048 * 4);
  float* KVc    = (float*)carve(8ull * 16 * 4096 * 4);
  float* Ksc    = (float*)carve(8ull * 16 * 64 * 4);
  u16*   attn   = (u16*)carve(2048ull * 512 * 2);
  u16*   hmid   = (u16*)carve(2048ull * 2048 * 2);
  u16*   part   = (u16*)carve(4ull * 2048 * 512 * 2);      // bf16 split-K partials
  (void)ws_size; (void)in_sizes; (void)n_in; (void)out_size;

  u16* phiq = phiAll;
  u16* phik = phiAll + 1048576;
  u16* vbf  = phiAll + 2097152;

  prep_kernel<<<6048, 256, 0, stream>>>(qkvw, outw, w1, w2, hw,
                                        wq_t, wo_t, w1_t, w2_t, wh_t,
                                        ids, tok, ln1s, ln1b, x, xn);

  for (int l = 0; l < 2; ++l) {
    const u16* wq_l = wq_t + (size_t)l * 1536 * 512;
    const u16* wo_l = wo_t + (size_t)l * 512 * 512;
    const u16* w1_l = w1_t + (size_t)l * 2048 * 512;
    const u16* w2_l = w2_t + (size_t)l * 512 * 2048;
    const float* nls = (l == 0) ? ln1s + 512 : lnfs;
    const float* nlb = (l == 0) ? ln1b + 512 : lnfb;

    gemm_bt<4><<<dim3(12, 16), 512, 0, stream>>>(xn, wq_l, nullptr, phiAll, nullptr,
                                                 2048, 1536, 512, 512);
    attn_intra<<<dim3(16, 8), 256, 0, stream>>>(phiq, phik, vbf, numer, denom, KVc, Ksc);
    attn_inter<<<dim3(16, 8), 256, 0, stream>>>(phiq, numer, denom, KVc, Ksc, attn);
    gemm_bt<5><<<dim3(4, 16, 2), 512, 0, stream>>>(attn, wo_l, nullptr, part, nullptr,
                                                   2048, 512, 512, 256);
    reduce_ln<<<512, 256, 0, stream>>>(part, 2, nullptr, x, ln2s + l * 512, ln2b + l * 512, xn);
    gemm_bt<2><<<dim3(16, 16), 512, 0, stream>>>(xn, w1_l, nullptr, hmid, b1 + l * 2048,
                                                 2048, 2048, 512, 512);
    gemm_bt<5><<<dim3(4, 16, 4), 512, 0, stream>>>(hmid, w2_l, nullptr, part, nullptr,
                                                   2048, 512, 2048, 512);
    reduce_ln<<<512, 256, 0, stream>>>(part, 4, b2 + l * 512, x, nls, nlb, xn);
  }

  gemm256<<<1000, 512, 0, stream>>>(xn, wh_t, out, 2048, 32000, 512);
}

// Round 15
// 277.086 us; speedup vs baseline: 3.0648x; 1.0640x over previous
//
#include <hip/hip_runtime.h>
#include <cstdint>

typedef unsigned short u16;
typedef __bf16 bf16x8 __attribute__((ext_vector_type(8)));
typedef float f32x4 __attribute__((ext_vector_type(4)));

#define DEV __device__ __forceinline__

DEV u16 f2bf(float f) {
  union { float f; unsigned u; } v; v.f = f;
  unsigned u = v.u;
  u += 0x7FFFu + ((u >> 16) & 1u);
  return (u16)(u >> 16);
}
DEV float bf2f(u16 u) {
  union { unsigned u; float f; } v; v.u = ((unsigned)u) << 16;
  return v.f;
}

// async global->LDS, 16B per lane; LDS dest must be wave-uniform base.
DEV void load16(const u16* g, u16* l) {
  __builtin_amdgcn_global_load_lds(
      (const __attribute__((address_space(1))) unsigned int*)(const void*)g,
      (__attribute__((address_space(3))) unsigned int*)l, 16, 0, 0);
}

// ---------------- prep: all weight transposes + embedding/PE/LN (one launch) ----------------
__global__ __launch_bounds__(256) void prep_kernel(
    const float* __restrict__ qkvw, const float* __restrict__ outw,
    const float* __restrict__ w1, const float* __restrict__ w2,
    const float* __restrict__ hw, u16* __restrict__ wq_t, u16* __restrict__ wo_t,
    u16* __restrict__ w1_t, u16* __restrict__ w2_t, u16* __restrict__ wh_t,
    const int* __restrict__ ids, const float* __restrict__ emb,
    const float* __restrict__ sc, const float* __restrict__ bi,
    float* __restrict__ x, u16* __restrict__ xn) {
  int b = blockIdx.x;
  __shared__ float t[64][65];
  if (b >= 5536) {  // ---- embedding + sinusoidal PE + layernorm ----
    int lane = threadIdx.x & 63, wave = threadIdx.x >> 6;
    int row = (b - 5536) * 4 + wave;
    int id = ids[row];
    float v[8];
#pragma unroll
    for (int i = 0; i < 8; ++i) {
      int c = lane + i * 64;
      float tk = emb[(size_t)id * 512 + c];
      int dp = c & ~1;
      float dv = expf((float)dp * (-9.210340371976184f / 512.0f));
      float ang = (float)row * dv;
      float pe = (c & 1) ? cosf(ang) : sinf(ang);
      v[i] = tk + pe;
      x[(size_t)row * 512 + c] = v[i];
    }
    float s = 0.f;
#pragma unroll
    for (int i = 0; i < 8; ++i) s += v[i];
#pragma unroll
    for (int m = 32; m; m >>= 1) s += __shfl_xor(s, m, 64);
    float mu = s * (1.0f / 512.0f);
    float var = 0.f;
#pragma unroll
    for (int i = 0; i < 8; ++i) { float d = v[i] - mu; var += d * d; }
#pragma unroll
    for (int m = 32; m; m >>= 1) var += __shfl_xor(var, m, 64);
    float rs = rsqrtf(var * (1.0f / 512.0f) + 1e-5f);
    u16* orow = xn + (size_t)row * 512;
#pragma unroll
    for (int i = 0; i < 8; ++i) {
      int c = lane + i * 64;
      orow[c] = f2bf((v[i] - mu) * rs * sc[c] + bi[c]);
    }
    return;
  }
  // ---- weight transpose f32 [K][N] -> bf16 [N][K] ----
  const float* in; u16* out; int K, N, nx, ky;
  if (b < 384)       { int z = b / 192, r = b % 192; nx = r % 24; ky = r / 24;
                       in = qkvw + (size_t)z * 786432; out = wq_t + (size_t)z * 786432; N = 1536; K = 512; }
  else if (b < 512)  { int tt = b - 384, z = tt / 64, r = tt % 64; nx = r % 8; ky = r / 8;
                       in = outw + (size_t)z * 262144; out = wo_t + (size_t)z * 262144; N = 512; K = 512; }
  else if (b < 1024) { int tt = b - 512, z = tt / 256, r = tt % 256; nx = r % 32; ky = r / 32;
                       in = w1 + (size_t)z * 1048576; out = w1_t + (size_t)z * 1048576; N = 2048; K = 512; }
  else if (b < 1536) { int tt = b - 1024, z = tt / 256, r = tt % 256; nx = r % 8; ky = r / 8;
                       in = w2 + (size_t)z * 1048576; out = w2_t + (size_t)z * 1048576; N = 512; K = 2048; }
  else               { int tt = b - 1536; nx = tt % 500; ky = tt / 500;
                       in = hw; out = wh_t; N = 32000; K = 512; }
  int n0 = nx * 64, k0 = ky * 64;
  for (int e = threadIdx.x; e < 4096; e += 256) {
    int r = e >> 6, c = e & 63;
    t[r][c] = in[(size_t)(k0 + r) * N + n0 + c];
  }
  __syncthreads();
  for (int e = threadIdx.x; e < 4096; e += 256) {
    int r = e >> 6, c = e & 63;
    out[(size_t)(n0 + r) * K + k0 + c] = f2bf(t[c][r]);
  }
}

// ---------------- fused split-K reduce (bf16 partials) + residual + layernorm ----------------
__global__ __launch_bounds__(256) void reduce_ln(const u16* __restrict__ part, int nz,
    const float* __restrict__ bias, float* __restrict__ x,
    const float* __restrict__ sc, const float* __restrict__ bi, u16* __restrict__ xn) {
  int lane = threadIdx.x & 63, wave = threadIdx.x >> 6;
  int row = blockIdx.x * 4 + wave;
  float* xr = x + (size_t)row * 512;
  float v[8];
#pragma unroll
  for (int i = 0; i < 8; ++i) v[i] = xr[lane + i * 64];
  if (bias) {
#pragma unroll
    for (int i = 0; i < 8; ++i) v[i] += bias[lane + i * 64];
  }
  for (int z = 0; z < nz; ++z) {
    const u16* pz = part + (size_t)z * 1048576 + (size_t)row * 512;
#pragma unroll
    for (int i = 0; i < 8; ++i) v[i] += bf2f(pz[lane + i * 64]);
  }
#pragma unroll
  for (int i = 0; i < 8; ++i) xr[lane + i * 64] = v[i];
  float s = 0.f;
#pragma unroll
  for (int i = 0; i < 8; ++i) s += v[i];
#pragma unroll
  for (int m = 32; m; m >>= 1) s += __shfl_xor(s, m, 64);
  float mu = s * (1.0f / 512.0f);
  float var = 0.f;
#pragma unroll
  for (int i = 0; i < 8; ++i) { float d = v[i] - mu; var += d * d; }
#pragma unroll
  for (int m = 32; m; m >>= 1) var += __shfl_xor(var, m, 64);
  float rs = rsqrtf(var * (1.0f / 512.0f) + 1e-5f);
  u16* orow = xn + (size_t)row * 512;
#pragma unroll
  for (int i = 0; i < 8; ++i) {
    int c = lane + i * 64;
    orow[c] = f2bf((v[i] - mu) * rs * sc[c] + bi[c]);
  }
}

// ---------------- intra-chunk causal linear attention + chunk sums (MFMA) ----------------
// grid (16 chunks, 8 heads, 2): wave w of block z owns row-tile fi = 2w+z.
// z==0 additionally computes KVc; z==1 computes Ksc.
__global__ __launch_bounds__(256) void attn_intra(const u16* __restrict__ pq,
    const u16* __restrict__ pk, const u16* __restrict__ pv,
    u16* __restrict__ numer, float* __restrict__ denom,
    float* __restrict__ KVc, float* __restrict__ Ksc) {
  int c = blockIdx.x, h = blockIdx.y, z = blockIdx.z;
  int s0 = c * 128;
  __shared__ u16 kl[128 * 72];
  __shared__ u16 vl[128 * 72];
  __shared__ u16 kT[64 * 136];
  __shared__ u16 vT[64 * 136];
  __shared__ u16 P[128 * 136];
  int tid = threadIdx.x, lane = tid & 63, w = tid >> 6;
  int fr = lane & 15, kb = lane >> 4, rg = lane >> 4;
  const size_t base = ((size_t)h * 2048 + s0) * 64;

  for (int e = tid; e < 1024; e += 256) {
    int r = e >> 3, c8 = (e & 7) * 8;
    *(bf16x8*)&kl[r * 72 + c8] = *(const bf16x8*)&pk[base + r * 64 + c8];
    *(bf16x8*)&vl[r * 72 + c8] = *(const bf16x8*)&pv[base + r * 64 + c8];
  }
  int fi = 2 * w + z;   // interleaved row-tile ownership (balances causal work)
  const u16* qA = pq + base + (size_t)(fi * 16 + fr) * 64 + kb * 8;
  bf16x8 aQ0 = *(const bf16x8*)qA, aQ1 = *(const bf16x8*)(qA + 32);
  __syncthreads();

  {
    int dh = tid & 63, sb = tid >> 6;
#pragma unroll
    for (int b8 = 0; b8 < 4; ++b8) {
      int sbase = sb * 32 + b8 * 8;
      u16 tk[8], tv[8];
#pragma unroll
      for (int j = 0; j < 8; ++j) {
        tk[j] = kl[(sbase + j) * 72 + dh];
        tv[j] = vl[(sbase + j) * 72 + dh];
      }
      *(int4*)&kT[dh * 136 + sbase] = *(const int4*)tk;
      *(int4*)&vT[dh * 136 + sbase] = *(const int4*)tv;
    }
  }

  // ---- S = Q K^T, causal mask, denom row-sums, P (bf16) ----
  {
    f32x4 dsum = {0.f, 0.f, 0.f, 0.f};
    for (int fj = 0; fj <= fi; ++fj) {
      f32x4 s4 = {0.f, 0.f, 0.f, 0.f};
      bf16x8 b0 = *(const bf16x8*)&kl[(fj * 16 + fr) * 72 + kb * 8];
      bf16x8 b1 = *(const bf16x8*)&kl[(fj * 16 + fr) * 72 + kb * 8 + 32];
      s4 = __builtin_amdgcn_mfma_f32_16x16x32_bf16(aQ0, b0, s4, 0, 0, 0);
      s4 = __builtin_amdgcn_mfma_f32_16x16x32_bf16(aQ1, b1, s4, 0, 0, 0);
      int colL = fj * 16 + fr;
#pragma unroll
      for (int rr = 0; rr < 4; ++rr) {
        int rowL = fi * 16 + rg * 4 + rr;
        float mv = (colL <= rowL) ? s4[rr] : 0.f;
        dsum[rr] += mv;
        P[rowL * 136 + colL] = f2bf(mv);
      }
    }
    if ((fi & 1) == 0) {   // zero upper-diag fragment inside PV k-range
      int colL = (fi + 1) * 16 + fr;
#pragma unroll
      for (int rr = 0; rr < 4; ++rr) P[(fi * 16 + rg * 4 + rr) * 136 + colL] = 0;
    }
#pragma unroll
    for (int rr = 0; rr < 4; ++rr) {
      float v = dsum[rr];
      v += __shfl_xor(v, 1, 16); v += __shfl_xor(v, 2, 16);
      v += __shfl_xor(v, 4, 16); v += __shfl_xor(v, 8, 16);
      if (fr == 0) denom[(size_t)h * 2048 + s0 + fi * 16 + rg * 4 + rr] = v;
    }
  }
  __syncthreads();

  // ---- numer = P V (k clipped causally) ----
  {
    int ktmax = (fi + 2) >> 1;
    f32x4 o0 = {0,0,0,0}, o1 = {0,0,0,0}, o2 = {0,0,0,0}, o3 = {0,0,0,0};
    for (int kt = 0; kt < ktmax; ++kt) {
      bf16x8 aP = *(const bf16x8*)&P[(fi * 16 + fr) * 136 + kt * 32 + kb * 8];
      o0 = __builtin_amdgcn_mfma_f32_16x16x32_bf16(aP, *(const bf16x8*)&vT[(0 * 16 + fr) * 136 + kt * 32 + kb * 8], o0, 0, 0, 0);
      o1 = __builtin_amdgcn_mfma_f32_16x16x32_bf16(aP, *(const bf16x8*)&vT[(1 * 16 + fr) * 136 + kt * 32 + kb * 8], o1, 0, 0, 0);
      o2 = __builtin_amdgcn_mfma_f32_16x16x32_bf16(aP, *(const bf16x8*)&vT[(2 * 16 + fr) * 136 + kt * 32 + kb * 8], o2, 0, 0, 0);
      o3 = __builtin_amdgcn_mfma_f32_16x16x32_bf16(aP, *(const bf16x8*)&vT[(3 * 16 + fr) * 136 + kt * 32 + kb * 8], o3, 0, 0, 0);
    }
#pragma unroll
    for (int rr = 0; rr < 4; ++rr) {
      size_t rb = base + (size_t)(fi * 16 + rg * 4 + rr) * 64;
      numer[rb + 0 + fr]  = f2bf(o0[rr]);
      numer[rb + 16 + fr] = f2bf(o1[rr]);
      numer[rb + 32 + fr] = f2bf(o2[rr]);
      numer[rb + 48 + fr] = f2bf(o3[rr]);
    }
  }

  if (z == 0) {
    // ---- KVc[i][j] = sum_s K[s][i] V[s][j], wave w owns i-tile w ----
    f32x4 k0 = {0,0,0,0}, k1 = {0,0,0,0}, k2 = {0,0,0,0}, k3 = {0,0,0,0};
    for (int kt = 0; kt < 4; ++kt) {
      bf16x8 aK = *(const bf16x8*)&kT[(w * 16 + fr) * 136 + kt * 32 + kb * 8];
      k0 = __builtin_amdgcn_mfma_f32_16x16x32_bf16(aK, *(const bf16x8*)&vT[(0 * 16 + fr) * 136 + kt * 32 + kb * 8], k0, 0, 0, 0);
      k1 = __builtin_amdgcn_mfma_f32_16x16x32_bf16(aK, *(const bf16x8*)&vT[(1 * 16 + fr) * 136 + kt * 32 + kb * 8], k1, 0, 0, 0);
      k2 = __builtin_amdgcn_mfma_f32_16x16x32_bf16(aK, *(const bf16x8*)&vT[(2 * 16 + fr) * 136 + kt * 32 + kb * 8], k2, 0, 0, 0);
      k3 = __builtin_amdgcn_mfma_f32_16x16x32_bf16(aK, *(const bf16x8*)&vT[(3 * 16 + fr) * 136 + kt * 32 + kb * 8], k3, 0, 0, 0);
    }
    float* kvb = KVc + ((size_t)h * 16 + c) * 4096;
#pragma unroll
    for (int rr = 0; rr < 4; ++rr) {
      int row = w * 16 + rg * 4 + rr;
      kvb[row * 64 + 0 + fr]  = k0[rr];
      kvb[row * 64 + 16 + fr] = k1[rr];
      kvb[row * 64 + 32 + fr] = k2[rr];
      kvb[row * 64 + 48 + fr] = k3[rr];
    }
  } else if (tid < 64) {
    // ---- Ksc[i] = sum_s K[s][i] ----
    float s = 0.f;
    for (int t8 = 0; t8 < 16; ++t8) {
      bf16x8 kv = *(const bf16x8*)&kT[tid * 136 + t8 * 8];
#pragma unroll
      for (int tt = 0; tt < 8; ++tt) s += bf2f(((const u16*)&kv)[tt]);
    }
    Ksc[((size_t)h * 16 + c) * 64 + tid] = s;
  }
}

// ---------------- inter-chunk prefix + finalize; grid (16,8,2): z owns 32-col half ----------------
__global__ __launch_bounds__(256) void attn_inter(const u16* __restrict__ pq,
    const u16* __restrict__ numer, const float* __restrict__ denom,
    const float* __restrict__ KVc, const float* __restrict__ Ksc,
    u16* __restrict__ attn) {
  int c = blockIdx.x, h = blockIdx.y, z = blockIdx.z;
  int s0 = c * 128;
  __shared__ float KVp[2048];      // [64][32] this half's cols
  __shared__ float Kp[64];
  __shared__ float ql[128 * 65];
  int tid = threadIdx.x;
  for (int e = tid; e < 512; e += 256) {
    int i = e >> 3, jl = (e & 7) * 4;
    f32x4 a = {0.f, 0.f, 0.f, 0.f};
    for (int cp = 0; cp < c; ++cp)
      a += *(const f32x4*)&KVc[((size_t)h * 16 + cp) * 4096 + i * 64 + z * 32 + jl];
    *(f32x4*)&KVp[i * 32 + jl] = a;
  }
  if (tid < 64) {
    float a = 0.f;
    for (int cp = 0; cp < c; ++cp) a += Ksc[((size_t)h * 16 + cp) * 64 + tid];
    Kp[tid] = a;
  }
  for (int e = tid; e < 1024; e += 256) {
    bf16x8 q8 = *(const bf16x8*)&pq[((size_t)h * 2048 + s0) * 64 + e * 8];
    int row = e >> 3, cb = (e & 7) * 8;
#pragma unroll
    for (int tt = 0; tt < 8; ++tt) ql[row * 65 + cb + tt] = bf2f(((const u16*)&q8)[tt]);
  }
  __syncthreads();
  int s = tid >> 1, half = tid & 1;
  int col0 = z * 32 + half * 16;          // global dh column base (16 cols)
  float num[16];
  {
    const u16* np_ = numer + ((size_t)h * 2048 + s0 + s) * 64 + col0;
#pragma unroll
    for (int i = 0; i < 2; ++i) {
      bf16x8 n8 = *(const bf16x8*)&np_[i * 8];
#pragma unroll
      for (int tt = 0; tt < 8; ++tt) num[i * 8 + tt] = bf2f(((const u16*)&n8)[tt]);
    }
  }
  float den = denom[(size_t)h * 2048 + s0 + s] + 1e-6f;
  for (int i = 0; i < 64; ++i) {
    float qv = ql[s * 65 + i];
    den += qv * Kp[i];
    const f32x4* kv = (const f32x4*)&KVp[i * 32 + half * 16];
#pragma unroll
    for (int j4 = 0; j4 < 4; ++j4) {
      f32x4 kvv = kv[j4];
#pragma unroll
      for (int t = 0; t < 4; ++t) num[j4 * 4 + t] += qv * kvv[t];
    }
  }
  float inv = 1.f / den;
  u16* op = attn + (size_t)(s0 + s) * 512 + h * 64 + col0;
#pragma unroll
  for (int j = 0; j < 16; ++j) op[j] = f2bf(num[j] * inv);
}

// ---------------- 128x128 pipelined bf16 GEMM: C = A[M][K] * Bt[N][K]^T ----------------
// EPI: 2 = bias+gelu->bf16; 4 = phi(qkv)->bf16; 5 = split-K partial (bf16)
template <int EPI>
__global__ __launch_bounds__(512, 2) void gemm_bt(const u16* __restrict__ A,
    const u16* __restrict__ B, float* __restrict__ outF, u16* __restrict__ outB,
    const float* __restrict__ bias, int M, int N, int K, int Ksplit) {
  __shared__ u16 lds[32768];  // A:[2][8192] | B at 16384:[2][8192]
  int tid = threadIdx.x, lane = tid & 63, w = tid >> 6;
  int f = blockIdx.x + gridDim.x * blockIdx.y;
  int m0 = (f & 15) << 7, n0 = (f >> 4) << 7;
  int wr = w >> 2, wc = w & 3;
  int fr = lane & 15, kb = lane >> 4;
  int z = blockIdx.z;
  int kbeg = z * Ksplit;
  int KT = Ksplit >> 6;

  auto stage = [&](int d, int u, int k0) {
    int t = u & 1;
    int row = t * 64 + w * 8 + (lane >> 3);
    int slot = (lane & 7) ^ ((lane >> 3) & 7);
    const u16* g = (u < 2 ? A + (size_t)(m0 + row) * K : B + (size_t)(n0 + row) * K)
                   + k0 + slot * 8;
    int dst = (u < 2 ? d * 8192 : 16384 + d * 8192) + t * 4096 + w * 512;
    load16(g, &lds[dst]);
  };
  auto rdA = [&](int d, int i, int kk) {
    int row = wr * 64 + i * 16 + fr;
    return *(const bf16x8*)&lds[d * 8192 + row * 64 + ((((kk << 2) | kb) ^ (fr & 7)) << 3)];
  };
  auto rdB = [&](int d, int j, int kk) {
    int row = wc * 32 + j * 16 + fr;
    return *(const bf16x8*)&lds[16384 + d * 8192 + row * 64 + ((((kk << 2) | kb) ^ (fr & 7)) << 3)];
  };

  f32x4 acc[4][2];
#pragma unroll
  for (int i = 0; i < 4; ++i)
#pragma unroll
    for (int j = 0; j < 2; ++j) acc[i][j] = (f32x4){0.f, 0.f, 0.f, 0.f};

#pragma unroll 1
  for (int u = 0; u < 4; ++u) stage(0, u, kbeg);
  __syncthreads();

  for (int t = 0; t < KT; ++t) {
    int d = t & 1, e = d ^ 1;
    int k1 = kbeg + ((t + 1) << 6);
    bool pre = (t + 1) < KT;
    bf16x8 aF[4], bF[2];
    if (pre) { stage(e, 0, k1); stage(e, 1, k1); }
#pragma unroll
    for (int i = 0; i < 4; ++i) aF[i] = rdA(d, i, 0);
#pragma unroll
    for (int j = 0; j < 2; ++j) bF[j] = rdB(d, j, 0);
    __builtin_amdgcn_s_setprio(1);
#pragma unroll
    for (int i = 0; i < 4; ++i)
#pragma unroll
      for (int j = 0; j < 2; ++j)
        acc[i][j] = __builtin_amdgcn_mfma_f32_16x16x32_bf16(aF[i], bF[j], acc[i][j], 0, 0, 0);
    __builtin_amdgcn_s_setprio(0);
    __builtin_amdgcn_sched_barrier(0);
    if (pre) { stage(e, 2, k1); stage(e, 3, k1); }
#pragma unroll
    for (int i = 0; i < 4; ++i) aF[i] = rdA(d, i, 1);
#pragma unroll
    for (int j = 0; j < 2; ++j) bF[j] = rdB(d, j, 1);
    __builtin_amdgcn_s_setprio(1);
#pragma unroll
    for (int i = 0; i < 4; ++i)
#pragma unroll
      for (int j = 0; j < 2; ++j)
        acc[i][j] = __builtin_amdgcn_mfma_f32_16x16x32_bf16(aF[i], bF[j], acc[i][j], 0, 0, 0);
    __builtin_amdgcn_s_setprio(0);
    __syncthreads();
  }

  int rq = lane >> 4;
#pragma unroll
  for (int i = 0; i < 4; ++i) {
#pragma unroll
    for (int j = 0; j < 2; ++j) {
      int col = n0 + wc * 32 + j * 16 + fr;
#pragma unroll
      for (int r = 0; r < 4; ++r) {
        int row = m0 + wr * 64 + i * 16 + rq * 4 + r;
        size_t o = (size_t)row * N + col;
        float vacc = acc[i][j][r];
        if (EPI == 2) {
          float t = vacc + bias[col];
          outB[o] = f2bf(0.5f * t * (1.f + erff(t * 0.70710678118654752f)));
        } else if (EPI == 4) {
          int part = col >> 9, d = col & 511, h = d >> 6, dh = d & 63;
          float wv = (part == 2) ? vacc : (vacc > 0.f ? vacc + 1.f : expf(vacc));
          outB[(size_t)part * 1048576 + (((size_t)h * 2048 + row) * 64 + dh)] = f2bf(wv);
        } else {  // 5: bf16 split-K partial
          outB[(size_t)z * 1048576 + o] = f2bf(vacc);
        }
      }
    }
  }
}

// ---------------- 256x256 pipelined bf16 GEMM (head), nontemporal C-stores ----------------
__global__ __launch_bounds__(512, 2) void gemm256(const u16* __restrict__ A,
    const u16* __restrict__ B, float* __restrict__ C, int M, int N, int K) {
  __shared__ u16 lds[65536];  // [A0|A1|B0|B1] each 16384 u16
  int tid = threadIdx.x, lane = tid & 63, w = tid >> 6;
  int f = blockIdx.x;
  {
    int nwg = gridDim.x;
    int q = nwg >> 3;              // nwg % 8 == 0 required
    f = (f & 7) * q + (f >> 3);    // XCD-contiguous chunks
  }
  int m0 = (f & 7) << 8;           // m fastest for B-panel L2 reuse
  int n0 = (f >> 3) << 8;
  int wr = w >> 2, wc = w & 3;
  int fr = lane & 15, kb = lane >> 4;

  auto stage = [&](int d, int u, int k0) {
    int us = u & 3;
    int row = us * 64 + w * 8 + (lane >> 3);
    int slot = (lane & 7) ^ ((lane >> 3) & 7);
    const u16* g = (u < 4 ? A + (size_t)(m0 + row) * K : B + (size_t)(n0 + row) * K)
                   + k0 + slot * 8;
    int dst = (u < 4 ? d * 16384 : 32768 + d * 16384) + us * 4096 + w * 512;
    load16(g, &lds[dst]);
  };
  auto rdA = [&](int d, int i, int kk) {
    int row = wr * 128 + i * 16 + fr;
    return *(const bf16x8*)&lds[d * 16384 + row * 64 + ((((kk << 2) | kb) ^ (fr & 7)) << 3)];
  };
  auto rdB = [&](int d, int j, int kk) {
    int row = wc * 64 + j * 16 + fr;
    return *(const bf16x8*)&lds[32768 + d * 16384 + row * 64 + ((((kk << 2) | kb) ^ (fr & 7)) << 3)];
  };

  f32x4 acc[8][4];
#pragma unroll
  for (int i = 0; i < 8; ++i)
#pragma unroll
    for (int j = 0; j < 4; ++j) acc[i][j] = (f32x4){0.f, 0.f, 0.f, 0.f};

  int KT = K >> 6;
#pragma unroll 1
  for (int u = 0; u < 8; ++u) stage(0, u, 0);
  __syncthreads();

  for (int t = 0; t < KT; ++t) {
    int d = t & 1, e = d ^ 1;
    int k1 = (t + 1) << 6;
    bool pre = (t + 1) < KT;
    bf16x8 aF[4][2], bF[4][2];
    if (pre) { stage(e, 0, k1); stage(e, 1, k1); }
#pragma unroll
    for (int i = 0; i < 4; ++i) { aF[i][0] = rdA(d, i, 0); aF[i][1] = rdA(d, i, 1); }
#pragma unroll
    for (int j = 0; j < 2; ++j) { bF[j][0] = rdB(d, j, 0); bF[j][1] = rdB(d, j, 1); }
    __builtin_amdgcn_s_setprio(1);
#pragma unroll
    for (int i = 0; i < 4; ++i)
#pragma unroll
      for (int j = 0; j < 2; ++j)
#pragma unroll
        for (int kk = 0; kk < 2; ++kk)
          acc[i][j] = __builtin_amdgcn_mfma_f32_16x16x32_bf16(aF[i][kk], bF[j][kk], acc[i][j], 0, 0, 0);
    __builtin_amdgcn_s_setprio(0);
    __builtin_amdgcn_sched_barrier(0);
    if (pre) { stage(e, 2, k1); stage(e, 3, k1); }
#pragma unroll
    for (int j = 2; j < 4; ++j) { bF[j][0] = rdB(d, j, 0); bF[j][1] = rdB(d, j, 1); }
    __builtin_amdgcn_s_setprio(1);
#pragma unroll
    for (int i = 0; i < 4; ++i)
#pragma unroll
      for (int j = 2; j < 4; ++j)
#pragma unroll
        for (int kk = 0; kk < 2; ++kk)
          acc[i][j] = __builtin_amdgcn_mfma_f32_16x16x32_bf16(aF[i][kk], bF[j][kk], acc[i][j], 0, 0, 0);
    __builtin_amdgcn_s_setprio(0);
    __builtin_amdgcn_sched_barrier(0);
    if (pre) { stage(e, 4, k1); stage(e, 5, k1); }
#pragma unroll
    for (int i = 0; i < 4; ++i) { aF[i][0] = rdA(d, i + 4, 0); aF[i][1] = rdA(d, i + 4, 1); }
    __builtin_amdgcn_s_setprio(1);
#pragma unroll
    for (int i = 0; i < 4; ++i)
#pragma unroll
      for (int j = 0; j < 2; ++j)
#pragma unroll
        for (int kk = 0; kk < 2; ++kk)
          acc[i + 4][j] = __builtin_amdgcn_mfma_f32_16x16x32_bf16(aF[i][kk], bF[j][kk], acc[i + 4][j], 0, 0, 0);
    __builtin_amdgcn_s_setprio(0);
    __builtin_amdgcn_sched_barrier(0);
    if (pre) { stage(e, 6, k1); stage(e, 7, k1); }
    __builtin_amdgcn_s_setprio(1);
#pragma unroll
    for (int i = 0; i < 4; ++i)
#pragma unroll
      for (int j = 2; j < 4; ++j)
#pragma unroll
        for (int kk = 0; kk < 2; ++kk)
          acc[i + 4][j] = __builtin_amdgcn_mfma_f32_16x16x32_bf16(aF[i][kk], bF[j][kk], acc[i + 4][j], 0, 0, 0);
    __builtin_amdgcn_s_setprio(0);
    __syncthreads();
  }

  int rq = lane >> 4;
#pragma unroll
  for (int i = 0; i < 8; ++i) {
#pragma unroll
    for (int j = 0; j < 4; ++j) {
      int col = n0 + wc * 64 + j * 16 + fr;
#pragma unroll
      for (int r = 0; r < 4; ++r) {
        int row = m0 + wr * 128 + i * 16 + rq * 4 + r;
        __builtin_nontemporal_store(acc[i][j][r], &C[(size_t)row * N + col]);
      }
    }
  }
}

// ---------------- host launcher ----------------
extern "C" void kernel_launch(void* const* d_in, const int* in_sizes, int n_in,
                              void* d_out, int out_size, void* d_ws, size_t ws_size,
                              hipStream_t stream) {
  const int*   ids  = (const int*)d_in[0];
  const float* tok  = (const float*)d_in[1];
  const float* ln1s = (const float*)d_in[2];
  const float* ln1b = (const float*)d_in[3];
  const float* qkvw = (const float*)d_in[4];
  const float* outw = (const float*)d_in[5];
  const float* ln2s = (const float*)d_in[6];
  const float* ln2b = (const float*)d_in[7];
  const float* w1   = (const float*)d_in[8];
  const float* b1   = (const float*)d_in[9];
  const float* w2   = (const float*)d_in[10];
  const float* b2   = (const float*)d_in[11];
  const float* lnfs = (const float*)d_in[12];
  const float* lnfb = (const float*)d_in[13];
  const float* hw   = (const float*)d_in[14];
  float* out = (float*)d_out;

  char* ws = (char*)d_ws;
  size_t off = 0;
  auto carve = [&](size_t bytes) {
    char* p = ws + off;
    off = (off + bytes + 255) & ~(size_t)255;
    return p;
  };
  u16*   wq_t   = (u16*)carve(2ull * 1536 * 512 * 2);
  u16*   wo_t   = (u16*)carve(2ull * 512 * 512 * 2);
  u16*   w1_t   = (u16*)carve(2ull * 2048 * 512 * 2);
  u16*   w2_t   = (u16*)carve(2ull * 512 * 2048 * 2);
  u16*   wh_t   = (u16*)carve(32000ull * 512 * 2);
  float* x      = (float*)carve(2048ull * 512 * 4);
  u16*   xn     = (u16*)carve(2048ull * 512 * 2);
  u16*   phiAll = (u16*)carve(3ull * 8 * 2048 * 64 * 2);   // pq | pk | pv
  u16*   numer  = (u16*)carve(8ull * 2048 * 64 * 2);       // bf16 numer
  float* denom  = (float*)carve(8ull * 2048 * 4);
  float* KVc    = (float*)carve(8ull * 16 * 4096 * 4);
  float* Ksc    = (float*)carve(8ull * 16 * 64 * 4);
  u16*   attn   = (u16*)carve(2048ull * 512 * 2);
  u16*   hmid   = (u16*)carve(2048ull * 2048 * 2);
  u16*   part   = (u16*)carve(4ull * 2048 * 512 * 2);      // bf16 split-K partials
  (void)ws_size; (void)in_sizes; (void)n_in; (void)out_size;

  u16* phiq = phiAll;
  u16* phik = phiAll + 1048576;
  u16* vbf  = phiAll + 2097152;

  prep_kernel<<<6048, 256, 0, stream>>>(qkvw, outw, w1, w2, hw,
                                        wq_t, wo_t, w1_t, w2_t, wh_t,
                                        ids, tok, ln1s, ln1b, x, xn);

  for (int l = 0; l < 2; ++l) {
    const u16* wq_l = wq_t + (size_t)l * 1536 * 512;
    const u16* wo_l = wo_t + (size_t)l * 512 * 512;
    const u16* w1_l = w1_t + (size_t)l * 2048 * 512;
    const u16* w2_l = w2_t + (size_t)l * 512 * 2048;
    const float* nls = (l == 0) ? ln1s + 512 : lnfs;
    const float* nlb = (l == 0) ? ln1b + 512 : lnfb;

    gemm_bt<4><<<dim3(12, 16), 512, 0, stream>>>(xn, wq_l, nullptr, phiAll, nullptr,
                                                 2048, 1536, 512, 512);
    attn_intra<<<dim3(16, 8, 2), 256, 0, stream>>>(phiq, phik, vbf, numer, denom, KVc, Ksc);
    attn_inter<<<dim3(16, 8, 2), 256, 0, stream>>>(phiq, numer, denom, KVc, Ksc, attn);
    gemm_bt<5><<<dim3(4, 16, 2), 512, 0, stream>>>(attn, wo_l, nullptr, part, nullptr,
                                                   2048, 512, 512, 256);
    reduce_ln<<<512, 256, 0, stream>>>(part, 2, nullptr, x, ln2s + l * 512, ln2b + l * 512, xn);
    gemm_bt<2><<<dim3(16, 16), 512, 0, stream>>>(xn, w1_l, nullptr, hmid, b1 + l * 2048,
                                                 2048, 2048, 512, 512);
    gemm_bt<5><<<dim3(4, 16, 4), 512, 0, stream>>>(hmid, w2_l, nullptr, part, nullptr,
                                                   2048, 512, 2048, 512);
    reduce_ln<<<512, 256, 0, stream>>>(part, 4, b2 + l * 512, x, nls, nlb, xn);
  }

  gemm256<<<1000, 512, 0, stream>>>(xn, wh_t, out, 2048, 32000, 512);
}